// Round 8
// baseline (98.485 us; speedup 1.0000x reference)
//
#include <hip/hip_runtime.h>
#include <hip/hip_bf16.h>
#include <math.h>

// Problem constants
#define N_TOK 196
#define M_KV  23520      // (C/4)*N
#define EPSN  1e-3f
#define LOG2E 1.44269504088896340736f

// Workspace layout (in floats)
#define OFF_QC    0
#define OFF_KC    94080
#define OFF_VC    188160
#define OFF_ATTN  282240   // 480*480 raw attn scores (psi1 pre-norm)
#define OFF_KV    512640   // float2[4*23520] = 188160 floats
#define OFF_SPART 700800   // 120*2 psi1 [sum,sumsq] per-block partials
#define OFF_KPART 701056   // [4 stats][4 heads][64 slots] = 1024 floats
#define OFF_LSLAB 702080   // 8*16*196 = 25088
#define OFF_CSLAB 727168   // 25088 (end 752256)
#define OFF_CNT   752256   // 16 spread sub-counters + master (zeroed by k_thatkv)
#define CHUNKS 8
#define CH 2940            // 23520/8
#define NBR (CHUNKS * 112) // 896 k_branch blocks; 896/16 = 56 per sub-counter

__device__ __forceinline__ float fast_exp2(float x) {
#if __has_builtin(__builtin_amdgcn_exp2f)
    return __builtin_amdgcn_exp2f(x);
#else
    return exp2f(x);
#endif
}

#define GEMM_COMPUTE(AS, BS) \
    _Pragma("unroll") \
    for (int kk2 = 0; kk2 < 16; ++kk2) { \
        float4 av = *(const float4*)&AS[kk2][ty*4]; \
        float2 bv = *(const float2*)&BS[kk2][tx*2]; \
        a00 = fmaf(av.x, bv.x, a00); a01 = fmaf(av.x, bv.y, a01); \
        a10 = fmaf(av.y, bv.x, a10); a11 = fmaf(av.y, bv.y, a11); \
        a20 = fmaf(av.z, bv.x, a20); a21 = fmaf(av.z, bv.y, a21); \
        a30 = fmaf(av.w, bv.x, a30); a31 = fmaf(av.w, bv.y, a31); \
    }

// ---------------- K1: Qc/Kc/Vc = emb_C @ W  (180 blocks) --------------------
__global__ __launch_bounds__(256) void k_qkv(const float* __restrict__ embC,
                                             const float* __restrict__ Wq,
                                             const float* __restrict__ Wk,
                                             const float* __restrict__ Wv,
                                             float* __restrict__ ws) {
    int bid = blockIdx.x;
    int zi = bid / 60, rem = bid % 60;
    int m0 = (rem / 15) * 64, n0 = (rem % 15) * 32;
    const float* W = (zi == 0) ? Wq : (zi == 1 ? Wk : Wv);
    float* o = ws + zi * 94080;
    __shared__ float As[2][16][68];
    __shared__ float Bs[2][16][36];
    int tid = threadIdx.x;
    int ty = tid >> 4, tx = tid & 15;
    float a00=0,a01=0,a10=0,a11=0,a20=0,a21=0,a30=0,a31=0;
    const float4 z4 = make_float4(0,0,0,0);
    int mrow = tid >> 2, kq = (tid & 3) * 4;
    bool am = (m0 + mrow) < N_TOK;
    const float* aptr = embC + (m0 + mrow) * 480 + kq;
    bool bact = tid < 128;
    int kk = tid >> 3, nq = (tid & 7) * 4;
    const float* bptr = W + kk * 480 + n0 + nq;
    const int NS = 30;
    float4 ra = am ? *(const float4*)(aptr) : z4;
    float4 rb = bact ? *(const float4*)(bptr) : z4;
    As[0][kq+0][mrow]=ra.x; As[0][kq+1][mrow]=ra.y; As[0][kq+2][mrow]=ra.z; As[0][kq+3][mrow]=ra.w;
    if (bact) *(float4*)&Bs[0][kk][nq] = rb;
    ra = am ? *(const float4*)(aptr + 16) : z4;
    rb = bact ? *(const float4*)(bptr + 16*480) : z4;
    __syncthreads();
    for (int s = 0; s < NS; ++s) {
        int b = s & 1;
        float4 fa = z4, fb = z4;
        if (s + 2 < NS) {
            fa = am ? *(const float4*)(aptr + (s+2)*16) : z4;
            fb = bact ? *(const float4*)(bptr + (s+2)*16*480) : z4;
        }
        GEMM_COMPUTE(As[b], Bs[b]);
        if (s + 1 < NS) {
            int nb = b ^ 1;
            As[nb][kq+0][mrow]=ra.x; As[nb][kq+1][mrow]=ra.y; As[nb][kq+2][mrow]=ra.z; As[nb][kq+3][mrow]=ra.w;
            if (bact) *(float4*)&Bs[nb][kk][nq] = rb;
        }
        __syncthreads();
        ra = fa; rb = fb;
    }
    int m = m0 + ty*4, n = n0 + tx*2;
    if (m   < N_TOK) *(float2*)(o + (m  )*480 + n) = make_float2(a00, a01);
    if (m+1 < N_TOK) *(float2*)(o + (m+1)*480 + n) = make_float2(a10, a11);
    if (m+2 < N_TOK) *(float2*)(o + (m+2)*480 + n) = make_float2(a20, a21);
    if (m+3 < N_TOK) *(float2*)(o + (m+3)*480 + n) = make_float2(a30, a31);
}

// ---------------- K2: attn = Qc^T @ Kc + psi1 partials (120 blocks) ---------
__global__ __launch_bounds__(256) void k_attn(const float* __restrict__ Qc,
                                              const float* __restrict__ Kc,
                                              float* __restrict__ attn,
                                              float* __restrict__ Spart) {
    __shared__ float As[2][16][68];
    __shared__ float Bs[2][16][36];
    __shared__ float red[4][2];
    int tid = threadIdx.x;
    int n0 = blockIdx.x * 32, m0 = blockIdx.y * 64;
    int ty = tid >> 4, tx = tid & 15;
    float a00=0,a01=0,a10=0,a11=0,a20=0,a21=0,a30=0,a31=0;
    const float4 z4 = make_float4(0,0,0,0);
    int kka = tid >> 4, mq = (tid & 15) * 4;
    bool amq = (m0 + mq) < 480;
    const float* aptr = Qc + kka * 480 + m0 + mq;
    bool bact = tid < 128;
    int kk = tid >> 3, nq = (tid & 7) * 4;
    const float* bptr = Kc + kk * 480 + n0 + nq;
    const int NS = 13;
    float4 ra = (amq && kka < N_TOK) ? *(const float4*)(aptr) : z4;
    float4 rb = (bact && kk < N_TOK) ? *(const float4*)(bptr) : z4;
    *(float4*)&As[0][kka][mq] = ra;
    if (bact) *(float4*)&Bs[0][kk][nq] = rb;
    ra = (amq && 16 + kka < N_TOK) ? *(const float4*)(aptr + 16*480) : z4;
    rb = (bact && 16 + kk < N_TOK) ? *(const float4*)(bptr + 16*480) : z4;
    __syncthreads();
    for (int s = 0; s < NS; ++s) {
        int b = s & 1;
        float4 fa = z4, fb = z4;
        if (s + 2 < NS) {
            int k0 = (s + 2) * 16;
            fa = (amq && k0 + kka < N_TOK) ? *(const float4*)(aptr + k0*480) : z4;
            fb = (bact && k0 + kk < N_TOK) ? *(const float4*)(bptr + k0*480) : z4;
        }
        GEMM_COMPUTE(As[b], Bs[b]);
        if (s + 1 < NS) {
            int nb = b ^ 1;
            *(float4*)&As[nb][kka][mq] = ra;
            if (bact) *(float4*)&Bs[nb][kk][nq] = rb;
        }
        __syncthreads();
        ra = fa; rb = fb;
    }
    int m = m0 + ty*4, n = n0 + tx*2;
    if (m   < 480) *(float2*)(attn + (m  )*480 + n) = make_float2(a00, a01);
    if (m+1 < 480) *(float2*)(attn + (m+1)*480 + n) = make_float2(a10, a11);
    if (m+2 < 480) *(float2*)(attn + (m+2)*480 + n) = make_float2(a20, a21);
    if (m+3 < 480) *(float2*)(attn + (m+3)*480 + n) = make_float2(a30, a31);
    float ls = a00+a01+a10+a11+a20+a21+a30+a31;
    float lq = a00*a00+a01*a01+a10*a10+a11*a11+a20*a20+a21*a21+a30*a30+a31*a31;
    #pragma unroll
    for (int o = 32; o > 0; o >>= 1) { ls += __shfl_xor(ls, o, 64); lq += __shfl_xor(lq, o, 64); }
    int wid = tid >> 6, lane = tid & 63;
    if (lane == 0) { red[wid][0] = ls; red[wid][1] = lq; }
    __syncthreads();
    if (tid == 0) {
        int bid = blockIdx.y * gridDim.x + blockIdx.x;
        Spart[bid*2]   = red[0][0] + red[1][0] + red[2][0] + red[3][0];
        Spart[bid*2+1] = red[0][1] + red[1][1] + red[2][1] + red[3][1];
    }
}

// ------- K3: fused softmax + T_hat GEMM + KV projection + kpart (60 blocks) -
// Also zeroes the k_branch completion counters (runs strictly before k_branch).
__global__ __launch_bounds__(256) void k_thatkv(const float* __restrict__ Vc,
                                                const float* __restrict__ attn,
                                                const float* __restrict__ Spart,
                                                const float* __restrict__ g1,
                                                const float* __restrict__ Wk,
                                                const float* __restrict__ Wv,
                                                float2* __restrict__ KV,
                                                float* __restrict__ kpart,
                                                unsigned* __restrict__ cnt) {
    __shared__ float As[2][16][68];
    __shared__ float Bs[2][16][36];
    __shared__ float red[4][16];
    __shared__ float M2s[32], INVs[32];
    __shared__ float Tile[64][33];
    int bid = blockIdx.x;
    int n0 = (bid % 15) * 32, m0 = (bid / 15) * 64;
    int tid = threadIdx.x;
    int wid = tid >> 6, lane = tid & 63;
    // zero last-block counters for k_branch (16 sub @ stride 32, master @ 512)
    if (bid == 0) {
        if (tid < 16) cnt[tid * 32] = 0u;
        if (tid == 16) cnt[512] = 0u;
    }
    // ---- psi1 scale from partials ----
    float ps = 0.f, pq = 0.f;
    if (tid < 120) { ps = Spart[tid*2]; pq = Spart[tid*2+1]; }
    #pragma unroll
    for (int o = 32; o > 0; o >>= 1) { ps += __shfl_xor(ps, o, 64); pq += __shfl_xor(pq, o, 64); }
    if (lane == 0) { red[wid][0] = ps; red[wid][1] = pq; }
    __syncthreads();
    float S  = red[0][0] + red[1][0] + red[2][0] + red[3][0];
    float SQ = red[0][1] + red[1][1] + red[2][1] + red[3][1];
    const float invCC = 1.f / (480.f * 480.f);
    float mean = S * invCC;
    float var  = SQ * invCC - mean * mean;
    float s2 = g1[0] * rsqrtf(var + EPSN) * LOG2E;
    // ---- row stats for this block's 32 rows ----
    int g = tid >> 5, l32 = tid & 31;
    #pragma unroll 1
    for (int batch = 0; batch < 4; ++batch) {
        int r = batch * 8 + g;
        const float* rowp = attn + (n0 + r) * 480 + l32;
        float mx = -INFINITY;
        #pragma unroll
        for (int p = 0; p < 15; ++p) mx = fmaxf(mx, s2 * rowp[p*32]);
        #pragma unroll
        for (int o = 16; o > 0; o >>= 1) mx = fmaxf(mx, __shfl_xor(mx, o, 64));
        if (l32 == 0) M2s[r] = mx;
    }
    __syncthreads();
    #pragma unroll 1
    for (int batch = 0; batch < 4; ++batch) {
        int r = batch * 8 + g;
        const float* rowp = attn + (n0 + r) * 480 + l32;
        float m2 = M2s[r];
        float sm = 0.f;
        #pragma unroll
        for (int p = 0; p < 15; ++p) sm += fast_exp2(fmaf(s2, rowp[p*32], -m2));
        #pragma unroll
        for (int o = 16; o > 0; o >>= 1) sm += __shfl_xor(sm, o, 64);
        if (l32 == 0) INVs[r] = 1.f / sm;
    }
    __syncthreads();
    // ---- double-buffered GEMM: A=Vc, B=softmax(sim) on-the-fly ----
    int ty = tid >> 4, tx = tid & 15;
    float a00=0,a01=0,a10=0,a11=0,a20=0,a21=0,a30=0,a31=0;
    const float4 z4 = make_float4(0,0,0,0);
    int mrow = tid >> 2, kq = (tid & 3) * 4;
    bool am = (m0 + mrow) < N_TOK;
    const float* aptr = Vc + (m0 + mrow) * 480 + kq;
    bool bact = tid < 128;
    int nrow = tid >> 2, bkq = (tid & 3) * 4;
    const float* bptr = attn + (n0 + nrow) * 480 + bkq;
    float nM2r = 0.f, invr = 0.f;
    if (bact) { nM2r = -M2s[nrow]; invr = INVs[nrow]; }
    const int NS = 30;
    float4 ra = am ? *(const float4*)(aptr) : z4;
    float4 rb = bact ? *(const float4*)(bptr) : z4;
    As[0][kq+0][mrow]=ra.x; As[0][kq+1][mrow]=ra.y; As[0][kq+2][mrow]=ra.z; As[0][kq+3][mrow]=ra.w;
    if (bact) {
        Bs[0][bkq+0][nrow] = fast_exp2(fmaf(s2, rb.x, nM2r)) * invr;
        Bs[0][bkq+1][nrow] = fast_exp2(fmaf(s2, rb.y, nM2r)) * invr;
        Bs[0][bkq+2][nrow] = fast_exp2(fmaf(s2, rb.z, nM2r)) * invr;
        Bs[0][bkq+3][nrow] = fast_exp2(fmaf(s2, rb.w, nM2r)) * invr;
    }
    ra = am ? *(const float4*)(aptr + 16) : z4;
    rb = bact ? *(const float4*)(bptr + 16) : z4;
    __syncthreads();
    for (int s = 0; s < NS; ++s) {
        int b = s & 1;
        float4 fa = z4, fb = z4;
        if (s + 2 < NS) {
            fa = am ? *(const float4*)(aptr + (s+2)*16) : z4;
            fb = bact ? *(const float4*)(bptr + (s+2)*16) : z4;
        }
        GEMM_COMPUTE(As[b], Bs[b]);
        if (s + 1 < NS) {
            int nb = b ^ 1;
            As[nb][kq+0][mrow]=ra.x; As[nb][kq+1][mrow]=ra.y; As[nb][kq+2][mrow]=ra.z; As[nb][kq+3][mrow]=ra.w;
            if (bact) {
                Bs[nb][bkq+0][nrow] = fast_exp2(fmaf(s2, rb.x, nM2r)) * invr;
                Bs[nb][bkq+1][nrow] = fast_exp2(fmaf(s2, rb.y, nM2r)) * invr;
                Bs[nb][bkq+2][nrow] = fast_exp2(fmaf(s2, rb.z, nM2r)) * invr;
                Bs[nb][bkq+3][nrow] = fast_exp2(fmaf(s2, rb.w, nM2r)) * invr;
            }
        }
        __syncthreads();
        ra = fa; rb = fb;
    }
    // ---- stage tile, project to K/V, per-block k-stats ----
    int r0 = ty*4, cc = tx*2;
    Tile[r0+0][cc] = a00; Tile[r0+0][cc+1] = a01;
    Tile[r0+1][cc] = a10; Tile[r0+1][cc+1] = a11;
    Tile[r0+2][cc] = a20; Tile[r0+2][cc+1] = a21;
    Tile[r0+3][cc] = a30; Tile[r0+3][cc+1] = a31;
    __syncthreads();
    float su[4] = {0,0,0,0}, sq[4] = {0,0,0,0};
    float mx[4] = {-INFINITY,-INFINITY,-INFINITY,-INFINITY};
    float mn[4] = { INFINITY, INFINITY, INFINITY, INFINITY};
    #pragma unroll
    for (int rep = 0; rep < 2; ++rep) {
        int e = tid + rep * 256;
        int t = e >> 3, jj = e & 7;
        int tok = m0 + t;
        bool act = tok < N_TOK;
        float c0 = Tile[t][4*jj], c1 = Tile[t][4*jj+1];
        float c2 = Tile[t][4*jj+2], c3 = Tile[t][4*jj+3];
        int m_kv = (n0/4 + jj) * 196 + tok;
        #pragma unroll
        for (int h = 0; h < 4; ++h) {
            float kh = c0*Wk[h] + c1*Wk[4+h] + c2*Wk[8+h] + c3*Wk[12+h];
            float vh = c0*Wv[h] + c1*Wv[4+h] + c2*Wv[8+h] + c3*Wv[12+h];
            if (act) {
                KV[h * M_KV + m_kv] = make_float2(kh, vh);
                su[h] += kh; sq[h] += kh * kh;
                mx[h] = fmaxf(mx[h], kh); mn[h] = fminf(mn[h], kh);
            }
        }
    }
    #pragma unroll
    for (int h = 0; h < 4; ++h) {
        #pragma unroll
        for (int o = 32; o > 0; o >>= 1) {
            su[h] += __shfl_xor(su[h], o, 64);
            sq[h] += __shfl_xor(sq[h], o, 64);
            mx[h] = fmaxf(mx[h], __shfl_xor(mx[h], o, 64));
            mn[h] = fminf(mn[h], __shfl_xor(mn[h], o, 64));
        }
        if (lane == 0) {
            red[wid][h*4+0] = su[h]; red[wid][h*4+1] = sq[h];
            red[wid][h*4+2] = mx[h]; red[wid][h*4+3] = mn[h];
        }
    }
    __syncthreads();
    if (tid < 16) {
        int h = tid & 3, st = tid >> 2;
        float v0 = red[0][h*4+st], v1 = red[1][h*4+st], v2 = red[2][h*4+st], v3 = red[3][h*4+st];
        float r;
        if (st < 2)       r = v0 + v1 + v2 + v3;
        else if (st == 2) r = fmaxf(fmaxf(v0, v1), fmaxf(v2, v3));
        else              r = fminf(fminf(v0, v1), fminf(v2, v3));
        kpart[st * 256 + h * 64 + bid] = r;
    }
}

// -------- K4: branch attention + last-block finalize (896 blocks) -----------
__global__ __launch_bounds__(256) void k_branch(
        const float* __restrict__ emb1, const float* __restrict__ emb2,
        const float* __restrict__ emb3, const float* __restrict__ emb4,
        const float* __restrict__ Wq1, const float* __restrict__ Wq2,
        const float* __restrict__ Wq3, const float* __restrict__ Wq4,
        const float* __restrict__ g2v,
        const float2* __restrict__ KV, const float* __restrict__ kpart,
        float* __restrict__ Lslab, float* __restrict__ Cslab,
        const float* __restrict__ Wo1, const float* __restrict__ Wo2,
        const float* __restrict__ Wo3, const float* __restrict__ Wo4,
        unsigned* __restrict__ cnt, float* __restrict__ out) {
    __shared__ float red[4][16];
    __shared__ int lastSh;
    int tid = threadIdx.x;
    int wid = tid >> 6, lane = tid & 63;
    int rq = blockIdx.y;
    int row = rq / 7, qg = rq % 7;
    int chunk = blockIdx.x;
    int i = row >> 2, h = row & 3;
    const float* emb = (i == 0) ? emb1 : (i == 1) ? emb2 : (i == 2) ? emb3 : emb4;
    const float* Wq  = (i == 0) ? Wq1 : (i == 1) ? Wq2 : (i == 2) ? Wq3 : Wq4;
    bool actq = tid < 196;
    float Q = 0.f;
    if (actq) {
        Q = emb[tid*4]*Wq[h] + emb[tid*4+1]*Wq[4+h] +
            emb[tid*4+2]*Wq[8+h] + emb[tid*4+3]*Wq[12+h];
    }
    float s = actq ? Q : 0.f, s2 = actq ? Q*Q : 0.f;
    float ks = 0.f, kq2 = 0.f, km = -INFINITY, kn = INFINITY;
    if (tid < 60) {
        ks  = kpart[0*256 + h*64 + tid];
        kq2 = kpart[1*256 + h*64 + tid];
        km  = kpart[2*256 + h*64 + tid];
        kn  = kpart[3*256 + h*64 + tid];
    }
    #pragma unroll
    for (int o = 32; o > 0; o >>= 1) {
        s += __shfl_xor(s, o, 64); s2 += __shfl_xor(s2, o, 64);
        ks += __shfl_xor(ks, o, 64); kq2 += __shfl_xor(kq2, o, 64);
        km = fmaxf(km, __shfl_xor(km, o, 64)); kn = fminf(kn, __shfl_xor(kn, o, 64));
    }
    if (lane == 0) {
        red[wid][0] = s;  red[wid][1] = s2; red[wid][2] = ks;
        red[wid][3] = kq2; red[wid][4] = km; red[wid][5] = kn;
    }
    __syncthreads();
    float sumQ  = red[0][0] + red[1][0] + red[2][0] + red[3][0];
    float sumQ2 = red[0][1] + red[1][1] + red[2][1] + red[3][1];
    float Ksum  = red[0][2] + red[1][2] + red[2][2] + red[3][2];
    float Ksq   = red[0][3] + red[1][3] + red[2][3] + red[3][3];
    float Kmax  = fmaxf(fmaxf(red[0][4], red[1][4]), fmaxf(red[2][4], red[3][4]));
    float Kmin  = fminf(fminf(red[0][5], red[1][5]), fminf(red[2][5], red[3][5]));
    float Qbar = sumQ * (1.f/196.f), Q2bar = sumQ2 * (1.f/196.f);
    float Kbar = Ksum * (1.f/(float)M_KV), K2bar = Ksq * (1.f/(float)M_KV);
    float mu = Qbar * Kbar;
    float var = Q2bar * K2bar - mu * mu;
    float sc = g2v[h] * rsqrtf(var + EPSN);
    int qbase = qg * 28 + wid * 7;
    float B2[7], nM2[7];
    #pragma unroll
    for (int j = 0; j < 7; ++j) {
        int q = qbase + j;
        float Qj = emb[q*4]*Wq[h] + emb[q*4+1]*Wq[4+h] +
                   emb[q*4+2]*Wq[8+h] + emb[q*4+3]*Wq[12+h];
        float b = Qj * sc;
        float M = (b >= 0.f) ? b * Kmax : b * Kmin;
        B2[j]  = b * LOG2E;
        nM2[j] = -M * LOG2E;
    }
    const float2* kvp = KV + h * M_KV;
    int kbase = chunk * CH, kend = kbase + CH;
    float l[7] = {0,0,0,0,0,0,0};
    float a[7] = {0,0,0,0,0,0,0};
#define PROC(P) { \
        _Pragma("unroll") \
        for (int j = 0; j < 7; ++j) { \
            float x = fast_exp2(fmaf(B2[j], P.x, nM2[j])); \
            l[j] += x; \
            a[j] = fmaf(x, P.y, a[j]); \
        } }
    int k = kbase + lane;
    for (; k + 192 < kend; k += 256) {
        float2 p0 = kvp[k], p1 = kvp[k+64], p2 = kvp[k+128], p3 = kvp[k+192];
        PROC(p0); PROC(p1); PROC(p2); PROC(p3);
    }
    for (; k < kend; k += 64) { float2 p = kvp[k]; PROC(p); }
#undef PROC
    int sbase = (chunk * 16 + row) * 196 + qbase;
    #pragma unroll
    for (int j = 0; j < 7; ++j) {
        float lv = l[j], av = a[j];
        #pragma unroll
        for (int o = 32; o > 0; o >>= 1) { lv += __shfl_xor(lv, o, 64); av += __shfl_xor(av, o, 64); }
        if (lane == 0) {
            Lslab[sbase + j] = lv;
            Cslab[sbase + j] = av;
        }
    }
    // ---- last-block-done: two-level counter, then finalize in this block ---
    __syncthreads();    // all slab stores issued (vmcnt drained at barrier)
    if (tid == 0) {
        __builtin_amdgcn_fence(__ATOMIC_RELEASE, "agent");   // flush slab writes
        int last = 0;
        int bidlin = rq * CHUNKS + chunk;
        unsigned* sub = cnt + (bidlin & 15) * 32;
        if (__hip_atomic_fetch_add(sub, 1u, __ATOMIC_RELAXED, __HIP_MEMORY_SCOPE_AGENT) == (NBR/16 - 1)) {
            if (__hip_atomic_fetch_add(cnt + 512, 1u, __ATOMIC_RELAXED, __HIP_MEMORY_SCOPE_AGENT) == 15u) {
                last = 1;
            }
        }
        lastSh = last;
    }
    __syncthreads();
    if (lastSh) {
        if (tid == 0) __builtin_amdgcn_fence(__ATOMIC_ACQUIRE, "agent");
        __syncthreads();
        int q = tid;
        if (q < 196) {
            #pragma unroll
            for (int ii = 0; ii < 4; ++ii) {
                const float* Wo = (ii == 0) ? Wo1 : (ii == 1) ? Wo2 : (ii == 2) ? Wo3 : Wo4;
                float c[4];
                #pragma unroll
                for (int hh = 0; hh < 4; ++hh) {
                    float L = 0.f, Cc = 0.f;
                    #pragma unroll
                    for (int ch = 0; ch < CHUNKS; ++ch) {
                        int idx = (ch * 16 + ii * 4 + hh) * 196 + q;
                        L  += Lslab[idx];
                        Cc += Cslab[idx];
                    }
                    c[hh] = Cc / L;
                }
                float4 o;
                o.x = c[0]*Wo[0] + c[1]*Wo[4] + c[2]*Wo[8]  + c[3]*Wo[12];
                o.y = c[0]*Wo[1] + c[1]*Wo[5] + c[2]*Wo[9]  + c[3]*Wo[13];
                o.z = c[0]*Wo[2] + c[1]*Wo[6] + c[2]*Wo[10] + c[3]*Wo[14];
                o.w = c[0]*Wo[3] + c[1]*Wo[7] + c[2]*Wo[11] + c[3]*Wo[15];
                *(float4*)(out + ii * 784 + q * 4) = o;
            }
        }
    }
}

extern "C" void kernel_launch(void* const* d_in, const int* in_sizes, int n_in,
                              void* d_out, int out_size, void* d_ws, size_t ws_size,
                              hipStream_t stream) {
    const float* emb1 = (const float*)d_in[0];
    const float* emb2 = (const float*)d_in[1];
    const float* emb3 = (const float*)d_in[2];
    const float* emb4 = (const float*)d_in[3];
    const float* embC = (const float*)d_in[4];
    const float* WqC  = (const float*)d_in[5];
    const float* WkC  = (const float*)d_in[6];
    const float* WvC  = (const float*)d_in[7];
    const float* Wq1  = (const float*)d_in[8];
    const float* Wq2  = (const float*)d_in[9];
    const float* Wq3  = (const float*)d_in[10];
    const float* Wq4  = (const float*)d_in[11];
    const float* Wk   = (const float*)d_in[12];
    const float* Wv   = (const float*)d_in[13];
    const float* Wo1  = (const float*)d_in[14];
    const float* Wo2  = (const float*)d_in[15];
    const float* Wo3  = (const float*)d_in[16];
    const float* Wo4  = (const float*)d_in[17];
    const float* g1   = (const float*)d_in[18];
    const float* g2   = (const float*)d_in[20];
    float* ws = (float*)d_ws;
    float* out = (float*)d_out;

    k_qkv<<<180, 256, 0, stream>>>(embC, WqC, WkC, WvC, ws);
    k_attn<<<dim3(15, 8), 256, 0, stream>>>(ws + OFF_QC, ws + OFF_KC,
                                            ws + OFF_ATTN, ws + OFF_SPART);
    k_thatkv<<<60, 256, 0, stream>>>(ws + OFF_VC, ws + OFF_ATTN, ws + OFF_SPART, g1,
                                     Wk, Wv, (float2*)(ws + OFF_KV), ws + OFF_KPART,
                                     (unsigned*)(ws + OFF_CNT));
    k_branch<<<dim3(CHUNKS, 112), 256, 0, stream>>>(emb1, emb2, emb3, emb4,
                                                    Wq1, Wq2, Wq3, Wq4, g2,
                                                    (const float2*)(ws + OFF_KV), ws + OFF_KPART,
                                                    ws + OFF_LSLAB, ws + OFF_CSLAB,
                                                    Wo1, Wo2, Wo3, Wo4,
                                                    (unsigned*)(ws + OFF_CNT), out);
}

// Round 9
// 88.755 us; speedup vs baseline: 1.1096x; 1.1096x over previous
//
#include <hip/hip_runtime.h>
#include <hip/hip_bf16.h>
#include <math.h>

// Problem constants
#define N_TOK 196
#define M_KV  23520      // (C/4)*N
#define EPSN  1e-3f
#define LOG2E 1.44269504088896340736f

// Workspace layout (in floats)
#define OFF_QC    0
#define OFF_KC    94080
#define OFF_VC    188160
#define OFF_ATTN  282240   // 480*480 raw attn scores (psi1 pre-norm)
#define OFF_KV    512640   // float2[4*23520] = 188160 floats
#define OFF_SPART 700800   // 120*2 psi1 [sum,sumsq] per-block partials
#define OFF_KPART 701056   // [4 stats][4 heads][64 slots] = 1024 floats

__device__ __forceinline__ float fast_exp2(float x) {
#if __has_builtin(__builtin_amdgcn_exp2f)
    return __builtin_amdgcn_exp2f(x);
#else
    return exp2f(x);
#endif
}

#define GEMM_COMPUTE(AS, BS) \
    _Pragma("unroll") \
    for (int kk2 = 0; kk2 < 16; ++kk2) { \
        float4 av = *(const float4*)&AS[kk2][ty*4]; \
        float2 bv = *(const float2*)&BS[kk2][tx*2]; \
        a00 = fmaf(av.x, bv.x, a00); a01 = fmaf(av.x, bv.y, a01); \
        a10 = fmaf(av.y, bv.x, a10); a11 = fmaf(av.y, bv.y, a11); \
        a20 = fmaf(av.z, bv.x, a20); a21 = fmaf(av.z, bv.y, a21); \
        a30 = fmaf(av.w, bv.x, a30); a31 = fmaf(av.w, bv.y, a31); \
    }

// ---------------- K1: Qc/Kc/Vc = emb_C @ W  (180 blocks) --------------------
__global__ __launch_bounds__(256) void k_qkv(const float* __restrict__ embC,
                                             const float* __restrict__ Wq,
                                             const float* __restrict__ Wk,
                                             const float* __restrict__ Wv,
                                             float* __restrict__ ws) {
    int bid = blockIdx.x;
    int zi = bid / 60, rem = bid % 60;
    int m0 = (rem / 15) * 64, n0 = (rem % 15) * 32;
    const float* W = (zi == 0) ? Wq : (zi == 1 ? Wk : Wv);
    float* o = ws + zi * 94080;
    __shared__ float As[2][16][68];
    __shared__ float Bs[2][16][36];
    int tid = threadIdx.x;
    int ty = tid >> 4, tx = tid & 15;
    float a00=0,a01=0,a10=0,a11=0,a20=0,a21=0,a30=0,a31=0;
    const float4 z4 = make_float4(0,0,0,0);
    int mrow = tid >> 2, kq = (tid & 3) * 4;
    bool am = (m0 + mrow) < N_TOK;
    const float* aptr = embC + (m0 + mrow) * 480 + kq;
    bool bact = tid < 128;
    int kk = tid >> 3, nq = (tid & 7) * 4;
    const float* bptr = W + kk * 480 + n0 + nq;
    const int NS = 30;
    float4 ra = am ? *(const float4*)(aptr) : z4;
    float4 rb = bact ? *(const float4*)(bptr) : z4;
    As[0][kq+0][mrow]=ra.x; As[0][kq+1][mrow]=ra.y; As[0][kq+2][mrow]=ra.z; As[0][kq+3][mrow]=ra.w;
    if (bact) *(float4*)&Bs[0][kk][nq] = rb;
    ra = am ? *(const float4*)(aptr + 16) : z4;
    rb = bact ? *(const float4*)(bptr + 16*480) : z4;
    __syncthreads();
    for (int s = 0; s < NS; ++s) {
        int b = s & 1;
        float4 fa = z4, fb = z4;
        if (s + 2 < NS) {
            fa = am ? *(const float4*)(aptr + (s+2)*16) : z4;
            fb = bact ? *(const float4*)(bptr + (s+2)*16*480) : z4;
        }
        GEMM_COMPUTE(As[b], Bs[b]);
        if (s + 1 < NS) {
            int nb = b ^ 1;
            As[nb][kq+0][mrow]=ra.x; As[nb][kq+1][mrow]=ra.y; As[nb][kq+2][mrow]=ra.z; As[nb][kq+3][mrow]=ra.w;
            if (bact) *(float4*)&Bs[nb][kk][nq] = rb;
        }
        __syncthreads();
        ra = fa; rb = fb;
    }
    int m = m0 + ty*4, n = n0 + tx*2;
    if (m   < N_TOK) *(float2*)(o + (m  )*480 + n) = make_float2(a00, a01);
    if (m+1 < N_TOK) *(float2*)(o + (m+1)*480 + n) = make_float2(a10, a11);
    if (m+2 < N_TOK) *(float2*)(o + (m+2)*480 + n) = make_float2(a20, a21);
    if (m+3 < N_TOK) *(float2*)(o + (m+3)*480 + n) = make_float2(a30, a31);
}

// ---------------- K2: attn = Qc^T @ Kc + psi1 partials (120 blocks) ---------
__global__ __launch_bounds__(256) void k_attn(const float* __restrict__ Qc,
                                              const float* __restrict__ Kc,
                                              float* __restrict__ attn,
                                              float* __restrict__ Spart) {
    __shared__ float As[2][16][68];
    __shared__ float Bs[2][16][36];
    __shared__ float red[4][2];
    int tid = threadIdx.x;
    int n0 = blockIdx.x * 32, m0 = blockIdx.y * 64;
    int ty = tid >> 4, tx = tid & 15;
    float a00=0,a01=0,a10=0,a11=0,a20=0,a21=0,a30=0,a31=0;
    const float4 z4 = make_float4(0,0,0,0);
    int kka = tid >> 4, mq = (tid & 15) * 4;
    bool amq = (m0 + mq) < 480;
    const float* aptr = Qc + kka * 480 + m0 + mq;
    bool bact = tid < 128;
    int kk = tid >> 3, nq = (tid & 7) * 4;
    const float* bptr = Kc + kk * 480 + n0 + nq;
    const int NS = 13;
    float4 ra = (amq && kka < N_TOK) ? *(const float4*)(aptr) : z4;
    float4 rb = (bact && kk < N_TOK) ? *(const float4*)(bptr) : z4;
    *(float4*)&As[0][kka][mq] = ra;
    if (bact) *(float4*)&Bs[0][kk][nq] = rb;
    ra = (amq && 16 + kka < N_TOK) ? *(const float4*)(aptr + 16*480) : z4;
    rb = (bact && 16 + kk < N_TOK) ? *(const float4*)(bptr + 16*480) : z4;
    __syncthreads();
    for (int s = 0; s < NS; ++s) {
        int b = s & 1;
        float4 fa = z4, fb = z4;
        if (s + 2 < NS) {
            int k0 = (s + 2) * 16;
            fa = (amq && k0 + kka < N_TOK) ? *(const float4*)(aptr + k0*480) : z4;
            fb = (bact && k0 + kk < N_TOK) ? *(const float4*)(bptr + k0*480) : z4;
        }
        GEMM_COMPUTE(As[b], Bs[b]);
        if (s + 1 < NS) {
            int nb = b ^ 1;
            *(float4*)&As[nb][kka][mq] = ra;
            if (bact) *(float4*)&Bs[nb][kk][nq] = rb;
        }
        __syncthreads();
        ra = fa; rb = fb;
    }
    int m = m0 + ty*4, n = n0 + tx*2;
    if (m   < 480) *(float2*)(attn + (m  )*480 + n) = make_float2(a00, a01);
    if (m+1 < 480) *(float2*)(attn + (m+1)*480 + n) = make_float2(a10, a11);
    if (m+2 < 480) *(float2*)(attn + (m+2)*480 + n) = make_float2(a20, a21);
    if (m+3 < 480) *(float2*)(attn + (m+3)*480 + n) = make_float2(a30, a31);
    float ls = a00+a01+a10+a11+a20+a21+a30+a31;
    float lq = a00*a00+a01*a01+a10*a10+a11*a11+a20*a20+a21*a21+a30*a30+a31*a31;
    #pragma unroll
    for (int o = 32; o > 0; o >>= 1) { ls += __shfl_xor(ls, o, 64); lq += __shfl_xor(lq, o, 64); }
    int wid = tid >> 6, lane = tid & 63;
    if (lane == 0) { red[wid][0] = ls; red[wid][1] = lq; }
    __syncthreads();
    if (tid == 0) {
        int bid = blockIdx.y * gridDim.x + blockIdx.x;
        Spart[bid*2]   = red[0][0] + red[1][0] + red[2][0] + red[3][0];
        Spart[bid*2+1] = red[0][1] + red[1][1] + red[2][1] + red[3][1];
    }
}

// ------- K3: fused softmax + T_hat GEMM + KV projection + kpart (60 blocks) -
__global__ __launch_bounds__(256) void k_thatkv(const float* __restrict__ Vc,
                                                const float* __restrict__ attn,
                                                const float* __restrict__ Spart,
                                                const float* __restrict__ g1,
                                                const float* __restrict__ Wk,
                                                const float* __restrict__ Wv,
                                                float2* __restrict__ KV,
                                                float* __restrict__ kpart) {
    __shared__ float As[2][16][68];
    __shared__ float Bs[2][16][36];
    __shared__ float red[4][16];
    __shared__ float M2s[32], INVs[32];
    __shared__ float Tile[64][33];
    int bid = blockIdx.x;
    int n0 = (bid % 15) * 32, m0 = (bid / 15) * 64;
    int tid = threadIdx.x;
    int wid = tid >> 6, lane = tid & 63;
    // ---- psi1 scale from partials ----
    float ps = 0.f, pq = 0.f;
    if (tid < 120) { ps = Spart[tid*2]; pq = Spart[tid*2+1]; }
    #pragma unroll
    for (int o = 32; o > 0; o >>= 1) { ps += __shfl_xor(ps, o, 64); pq += __shfl_xor(pq, o, 64); }
    if (lane == 0) { red[wid][0] = ps; red[wid][1] = pq; }
    __syncthreads();
    float S  = red[0][0] + red[1][0] + red[2][0] + red[3][0];
    float SQ = red[0][1] + red[1][1] + red[2][1] + red[3][1];
    const float invCC = 1.f / (480.f * 480.f);
    float mean = S * invCC;
    float var  = SQ * invCC - mean * mean;
    float s2 = g1[0] * rsqrtf(var + EPSN) * LOG2E;
    // ---- row stats for this block's 32 rows ----
    int g = tid >> 5, l32 = tid & 31;
    #pragma unroll 1
    for (int batch = 0; batch < 4; ++batch) {
        int r = batch * 8 + g;
        const float* rowp = attn + (n0 + r) * 480 + l32;
        float mx = -INFINITY;
        #pragma unroll
        for (int p = 0; p < 15; ++p) mx = fmaxf(mx, s2 * rowp[p*32]);
        #pragma unroll
        for (int o = 16; o > 0; o >>= 1) mx = fmaxf(mx, __shfl_xor(mx, o, 64));
        if (l32 == 0) M2s[r] = mx;
    }
    __syncthreads();
    #pragma unroll 1
    for (int batch = 0; batch < 4; ++batch) {
        int r = batch * 8 + g;
        const float* rowp = attn + (n0 + r) * 480 + l32;
        float m2 = M2s[r];
        float sm = 0.f;
        #pragma unroll
        for (int p = 0; p < 15; ++p) sm += fast_exp2(fmaf(s2, rowp[p*32], -m2));
        #pragma unroll
        for (int o = 16; o > 0; o >>= 1) sm += __shfl_xor(sm, o, 64);
        if (l32 == 0) INVs[r] = 1.f / sm;
    }
    __syncthreads();
    // ---- double-buffered GEMM: A=Vc, B=softmax(sim) on-the-fly ----
    int ty = tid >> 4, tx = tid & 15;
    float a00=0,a01=0,a10=0,a11=0,a20=0,a21=0,a30=0,a31=0;
    const float4 z4 = make_float4(0,0,0,0);
    int mrow = tid >> 2, kq = (tid & 3) * 4;
    bool am = (m0 + mrow) < N_TOK;
    const float* aptr = Vc + (m0 + mrow) * 480 + kq;
    bool bact = tid < 128;
    int nrow = tid >> 2, bkq = (tid & 3) * 4;
    const float* bptr = attn + (n0 + nrow) * 480 + bkq;
    float nM2r = 0.f, invr = 0.f;
    if (bact) { nM2r = -M2s[nrow]; invr = INVs[nrow]; }
    const int NS = 30;
    float4 ra = am ? *(const float4*)(aptr) : z4;
    float4 rb = bact ? *(const float4*)(bptr) : z4;
    As[0][kq+0][mrow]=ra.x; As[0][kq+1][mrow]=ra.y; As[0][kq+2][mrow]=ra.z; As[0][kq+3][mrow]=ra.w;
    if (bact) {
        Bs[0][bkq+0][nrow] = fast_exp2(fmaf(s2, rb.x, nM2r)) * invr;
        Bs[0][bkq+1][nrow] = fast_exp2(fmaf(s2, rb.y, nM2r)) * invr;
        Bs[0][bkq+2][nrow] = fast_exp2(fmaf(s2, rb.z, nM2r)) * invr;
        Bs[0][bkq+3][nrow] = fast_exp2(fmaf(s2, rb.w, nM2r)) * invr;
    }
    ra = am ? *(const float4*)(aptr + 16) : z4;
    rb = bact ? *(const float4*)(bptr + 16) : z4;
    __syncthreads();
    for (int s = 0; s < NS; ++s) {
        int b = s & 1;
        float4 fa = z4, fb = z4;
        if (s + 2 < NS) {
            fa = am ? *(const float4*)(aptr + (s+2)*16) : z4;
            fb = bact ? *(const float4*)(bptr + (s+2)*16) : z4;
        }
        GEMM_COMPUTE(As[b], Bs[b]);
        if (s + 1 < NS) {
            int nb = b ^ 1;
            As[nb][kq+0][mrow]=ra.x; As[nb][kq+1][mrow]=ra.y; As[nb][kq+2][mrow]=ra.z; As[nb][kq+3][mrow]=ra.w;
            if (bact) {
                Bs[nb][bkq+0][nrow] = fast_exp2(fmaf(s2, rb.x, nM2r)) * invr;
                Bs[nb][bkq+1][nrow] = fast_exp2(fmaf(s2, rb.y, nM2r)) * invr;
                Bs[nb][bkq+2][nrow] = fast_exp2(fmaf(s2, rb.z, nM2r)) * invr;
                Bs[nb][bkq+3][nrow] = fast_exp2(fmaf(s2, rb.w, nM2r)) * invr;
            }
        }
        __syncthreads();
        ra = fa; rb = fb;
    }
    // ---- stage tile, project to K/V, per-block k-stats ----
    int r0 = ty*4, cc = tx*2;
    Tile[r0+0][cc] = a00; Tile[r0+0][cc+1] = a01;
    Tile[r0+1][cc] = a10; Tile[r0+1][cc+1] = a11;
    Tile[r0+2][cc] = a20; Tile[r0+2][cc+1] = a21;
    Tile[r0+3][cc] = a30; Tile[r0+3][cc+1] = a31;
    __syncthreads();
    float su[4] = {0,0,0,0}, sq[4] = {0,0,0,0};
    float mx[4] = {-INFINITY,-INFINITY,-INFINITY,-INFINITY};
    float mn[4] = { INFINITY, INFINITY, INFINITY, INFINITY};
    #pragma unroll
    for (int rep = 0; rep < 2; ++rep) {
        int e = tid + rep * 256;
        int t = e >> 3, jj = e & 7;
        int tok = m0 + t;
        bool act = tok < N_TOK;
        float c0 = Tile[t][4*jj], c1 = Tile[t][4*jj+1];
        float c2 = Tile[t][4*jj+2], c3 = Tile[t][4*jj+3];
        int m_kv = (n0/4 + jj) * 196 + tok;
        #pragma unroll
        for (int h = 0; h < 4; ++h) {
            float kh = c0*Wk[h] + c1*Wk[4+h] + c2*Wk[8+h] + c3*Wk[12+h];
            float vh = c0*Wv[h] + c1*Wv[4+h] + c2*Wv[8+h] + c3*Wv[12+h];
            if (act) {
                KV[h * M_KV + m_kv] = make_float2(kh, vh);
                su[h] += kh; sq[h] += kh * kh;
                mx[h] = fmaxf(mx[h], kh); mn[h] = fminf(mn[h], kh);
            }
        }
    }
    #pragma unroll
    for (int h = 0; h < 4; ++h) {
        #pragma unroll
        for (int o = 32; o > 0; o >>= 1) {
            su[h] += __shfl_xor(su[h], o, 64);
            sq[h] += __shfl_xor(sq[h], o, 64);
            mx[h] = fmaxf(mx[h], __shfl_xor(mx[h], o, 64));
            mn[h] = fminf(mn[h], __shfl_xor(mn[h], o, 64));
        }
        if (lane == 0) {
            red[wid][h*4+0] = su[h]; red[wid][h*4+1] = sq[h];
            red[wid][h*4+2] = mx[h]; red[wid][h*4+3] = mn[h];
        }
    }
    __syncthreads();
    if (tid < 16) {
        int h = tid & 3, st = tid >> 2;
        float v0 = red[0][h*4+st], v1 = red[1][h*4+st], v2 = red[2][h*4+st], v3 = red[3][h*4+st];
        float r;
        if (st < 2)       r = v0 + v1 + v2 + v3;
        else if (st == 2) r = fmaxf(fmaxf(v0, v1), fmaxf(v2, v3));
        else              r = fminf(fminf(v0, v1), fminf(v2, v3));
        kpart[st * 256 + h * 64 + bid] = r;
    }
}

// -------- K4: branch attention, full-K per block, in-block finalize ---------
// grid = 196 blocks: (branch i = bid/49, q-group qg = bid%49, 4 q's).
// Wave w = head w: own stats, 4 q's, all 23520 keys; finalize via 16-float LDS.
#define QG 49
__global__ __launch_bounds__(256) void k_branch(
        const float* __restrict__ emb1, const float* __restrict__ emb2,
        const float* __restrict__ emb3, const float* __restrict__ emb4,
        const float* __restrict__ Wq1, const float* __restrict__ Wq2,
        const float* __restrict__ Wq3, const float* __restrict__ Wq4,
        const float* __restrict__ g2v,
        const float2* __restrict__ KV, const float* __restrict__ kpart,
        const float* __restrict__ Wo1, const float* __restrict__ Wo2,
        const float* __restrict__ Wo3, const float* __restrict__ Wo4,
        float* __restrict__ out) {
    __shared__ float csh[4][4];   // [head][j]
    int tid = threadIdx.x;
    int h = tid >> 6, lane = tid & 63;        // wave = head
    int bid = blockIdx.x;
    int i = bid / QG, qg = bid % QG;
    const float* emb = (i == 0) ? emb1 : (i == 1) ? emb2 : (i == 2) ? emb3 : emb4;
    const float* Wq  = (i == 0) ? Wq1 : (i == 1) ? Wq2 : (i == 2) ? Wq3 : Wq4;
    float wq0 = Wq[h], wq1 = Wq[4+h], wq2 = Wq[8+h], wq3 = Wq[12+h];
    // ---- per-wave psi2 stats for (i, h) ----
    float s = 0.f, s2 = 0.f;
    #pragma unroll
    for (int r = 0; r < 4; ++r) {
        int t = lane + r * 64;
        if (t < N_TOK) {
            float Q = emb[t*4]*wq0 + emb[t*4+1]*wq1 + emb[t*4+2]*wq2 + emb[t*4+3]*wq3;
            s += Q; s2 += Q * Q;
        }
    }
    float ks = 0.f, kq2 = 0.f, km = -INFINITY, kn = INFINITY;
    if (lane < 60) {
        ks  = kpart[0*256 + h*64 + lane];
        kq2 = kpart[1*256 + h*64 + lane];
        km  = kpart[2*256 + h*64 + lane];
        kn  = kpart[3*256 + h*64 + lane];
    }
    #pragma unroll
    for (int o = 32; o > 0; o >>= 1) {
        s += __shfl_xor(s, o, 64); s2 += __shfl_xor(s2, o, 64);
        ks += __shfl_xor(ks, o, 64); kq2 += __shfl_xor(kq2, o, 64);
        km = fmaxf(km, __shfl_xor(km, o, 64)); kn = fminf(kn, __shfl_xor(kn, o, 64));
    }
    float Qbar = s * (1.f/196.f), Q2bar = s2 * (1.f/196.f);
    float Kbar = ks * (1.f/(float)M_KV), K2bar = kq2 * (1.f/(float)M_KV);
    float mu = Qbar * Kbar;
    float var = Q2bar * K2bar - mu * mu;
    float sc = g2v[h] * rsqrtf(var + EPSN);
    // ---- 4 q's: beta (log2e folded) + analytic row max ----
    float B2[4], nM2[4];
    #pragma unroll
    for (int j = 0; j < 4; ++j) {
        int q = qg * 4 + j;
        float Qj = emb[q*4]*wq0 + emb[q*4+1]*wq1 + emb[q*4+2]*wq2 + emb[q*4+3]*wq3;
        float b = Qj * sc;
        float M = (b >= 0.f) ? b * km : b * kn;
        B2[j]  = b * LOG2E;
        nM2[j] = -M * LOG2E;
    }
    // ---- full-K scan: float4 = 2 keys/lane/load, 4 loads in flight ----
    const float4* kv4 = (const float4*)(KV + h * M_KV);
    const int K4 = M_KV / 2;   // 11760
    float l[4] = {0,0,0,0};
    float a[4] = {0,0,0,0};
#define PROC8(P) { \
        _Pragma("unroll") \
        for (int j = 0; j < 4; ++j) { \
            float x = fast_exp2(fmaf(B2[j], P.x, nM2[j])); \
            l[j] += x; a[j] = fmaf(x, P.y, a[j]); \
            float y = fast_exp2(fmaf(B2[j], P.z, nM2[j])); \
            l[j] += y; a[j] = fmaf(y, P.w, a[j]); \
        } }
    int k4 = lane;
    for (; k4 + 192 < K4; k4 += 256) {
        float4 p0 = kv4[k4], p1 = kv4[k4+64], p2 = kv4[k4+128], p3 = kv4[k4+192];
        PROC8(p0); PROC8(p1); PROC8(p2); PROC8(p3);
    }
    for (; k4 < K4; k4 += 64) { float4 p = kv4[k4]; PROC8(p); }
#undef PROC8
    // ---- per-wave reduce, c = a/l -> LDS ----
    #pragma unroll
    for (int j = 0; j < 4; ++j) {
        float lv = l[j], av = a[j];
        #pragma unroll
        for (int o = 32; o > 0; o >>= 1) { lv += __shfl_xor(lv, o, 64); av += __shfl_xor(av, o, 64); }
        if (lane == 0) csh[h][j] = av / lv;
    }
    __syncthreads();
    // ---- in-block finalize: out[i, qg*4+j, :] = sum_h c[h][j] * Wo_i[h,:] ----
    if (tid < 4) {
        const float* Wo = (i == 0) ? Wo1 : (i == 1) ? Wo2 : (i == 2) ? Wo3 : Wo4;
        int j = tid;
        float c0 = csh[0][j], c1 = csh[1][j], c2 = csh[2][j], c3 = csh[3][j];
        float4 o;
        o.x = c0*Wo[0] + c1*Wo[4] + c2*Wo[8]  + c3*Wo[12];
        o.y = c0*Wo[1] + c1*Wo[5] + c2*Wo[9]  + c3*Wo[13];
        o.z = c0*Wo[2] + c1*Wo[6] + c2*Wo[10] + c3*Wo[14];
        o.w = c0*Wo[3] + c1*Wo[7] + c2*Wo[11] + c3*Wo[15];
        *(float4*)(out + i * 784 + (qg * 4 + j) * 4) = o;
    }
}

extern "C" void kernel_launch(void* const* d_in, const int* in_sizes, int n_in,
                              void* d_out, int out_size, void* d_ws, size_t ws_size,
                              hipStream_t stream) {
    const float* emb1 = (const float*)d_in[0];
    const float* emb2 = (const float*)d_in[1];
    const float* emb3 = (const float*)d_in[2];
    const float* emb4 = (const float*)d_in[3];
    const float* embC = (const float*)d_in[4];
    const float* WqC  = (const float*)d_in[5];
    const float* WkC  = (const float*)d_in[6];
    const float* WvC  = (const float*)d_in[7];
    const float* Wq1  = (const float*)d_in[8];
    const float* Wq2  = (const float*)d_in[9];
    const float* Wq3  = (const float*)d_in[10];
    const float* Wq4  = (const float*)d_in[11];
    const float* Wk   = (const float*)d_in[12];
    const float* Wv   = (const float*)d_in[13];
    const float* Wo1  = (const float*)d_in[14];
    const float* Wo2  = (const float*)d_in[15];
    const float* Wo3  = (const float*)d_in[16];
    const float* Wo4  = (const float*)d_in[17];
    const float* g1   = (const float*)d_in[18];
    const float* g2   = (const float*)d_in[20];
    float* ws = (float*)d_ws;
    float* out = (float*)d_out;

    k_qkv<<<180, 256, 0, stream>>>(embC, WqC, WkC, WvC, ws);
    k_attn<<<dim3(15, 8), 256, 0, stream>>>(ws + OFF_QC, ws + OFF_KC,
                                            ws + OFF_ATTN, ws + OFF_SPART);
    k_thatkv<<<60, 256, 0, stream>>>(ws + OFF_VC, ws + OFF_ATTN, ws + OFF_SPART, g1,
                                     Wk, Wv, (float2*)(ws + OFF_KV), ws + OFF_KPART);
    k_branch<<<4 * QG, 256, 0, stream>>>(emb1, emb2, emb3, emb4,
                                         Wq1, Wq2, Wq3, Wq4, g2,
                                         (const float2*)(ws + OFF_KV), ws + OFF_KPART,
                                         Wo1, Wo2, Wo3, Wo4, out);
}

// Round 10
// 78.874 us; speedup vs baseline: 1.2486x; 1.1253x over previous
//
#include <hip/hip_runtime.h>
#include <hip/hip_bf16.h>
#include <math.h>

// Problem constants
#define N_TOK 196
#define M_KV  23520      // (C/4)*N
#define EPSN  1e-3f
#define LOG2E 1.44269504088896340736f

// Workspace layout (in floats)
#define OFF_QC    0
#define OFF_KC    94080
#define OFF_VC    188160
#define OFF_ATTN  282240   // 480*480 raw attn scores (psi1 pre-norm)
#define OFF_KV    512640   // float2[4*23520] = 188160 floats
#define OFF_SPART 700800   // 120*2 psi1 [sum,sumsq] per-block partials
#define OFF_KPART 701056   // [4 stats][4 heads][64 slots] = 1024 floats

__device__ __forceinline__ float fast_exp2(float x) {
#if __has_builtin(__builtin_amdgcn_exp2f)
    return __builtin_amdgcn_exp2f(x);
#else
    return exp2f(x);
#endif
}

#define GEMM_COMPUTE(AS, BS) \
    _Pragma("unroll") \
    for (int kk2 = 0; kk2 < 16; ++kk2) { \
        float4 av = *(const float4*)&AS[kk2][ty*4]; \
        float2 bv = *(const float2*)&BS[kk2][tx*2]; \
        a00 = fmaf(av.x, bv.x, a00); a01 = fmaf(av.x, bv.y, a01); \
        a10 = fmaf(av.y, bv.x, a10); a11 = fmaf(av.y, bv.y, a11); \
        a20 = fmaf(av.z, bv.x, a20); a21 = fmaf(av.z, bv.y, a21); \
        a30 = fmaf(av.w, bv.x, a30); a31 = fmaf(av.w, bv.y, a31); \
    }

// ---------------- K1: Qc/Kc/Vc = emb_C @ W  (180 blocks) --------------------
__global__ __launch_bounds__(256) void k_qkv(const float* __restrict__ embC,
                                             const float* __restrict__ Wq,
                                             const float* __restrict__ Wk,
                                             const float* __restrict__ Wv,
                                             float* __restrict__ ws) {
    int bid = blockIdx.x;
    int zi = bid / 60, rem = bid % 60;
    int m0 = (rem / 15) * 64, n0 = (rem % 15) * 32;
    const float* W = (zi == 0) ? Wq : (zi == 1 ? Wk : Wv);
    float* o = ws + zi * 94080;
    __shared__ float As[2][16][68];
    __shared__ float Bs[2][16][36];
    int tid = threadIdx.x;
    int ty = tid >> 4, tx = tid & 15;
    float a00=0,a01=0,a10=0,a11=0,a20=0,a21=0,a30=0,a31=0;
    const float4 z4 = make_float4(0,0,0,0);
    int mrow = tid >> 2, kq = (tid & 3) * 4;
    bool am = (m0 + mrow) < N_TOK;
    const float* aptr = embC + (m0 + mrow) * 480 + kq;
    bool bact = tid < 128;
    int kk = tid >> 3, nq = (tid & 7) * 4;
    const float* bptr = W + kk * 480 + n0 + nq;
    const int NS = 30;
    float4 ra = am ? *(const float4*)(aptr) : z4;
    float4 rb = bact ? *(const float4*)(bptr) : z4;
    As[0][kq+0][mrow]=ra.x; As[0][kq+1][mrow]=ra.y; As[0][kq+2][mrow]=ra.z; As[0][kq+3][mrow]=ra.w;
    if (bact) *(float4*)&Bs[0][kk][nq] = rb;
    ra = am ? *(const float4*)(aptr + 16) : z4;
    rb = bact ? *(const float4*)(bptr + 16*480) : z4;
    __syncthreads();
    for (int s = 0; s < NS; ++s) {
        int b = s & 1;
        float4 fa = z4, fb = z4;
        if (s + 2 < NS) {
            fa = am ? *(const float4*)(aptr + (s+2)*16) : z4;
            fb = bact ? *(const float4*)(bptr + (s+2)*16*480) : z4;
        }
        GEMM_COMPUTE(As[b], Bs[b]);
        if (s + 1 < NS) {
            int nb = b ^ 1;
            As[nb][kq+0][mrow]=ra.x; As[nb][kq+1][mrow]=ra.y; As[nb][kq+2][mrow]=ra.z; As[nb][kq+3][mrow]=ra.w;
            if (bact) *(float4*)&Bs[nb][kk][nq] = rb;
        }
        __syncthreads();
        ra = fa; rb = fb;
    }
    int m = m0 + ty*4, n = n0 + tx*2;
    if (m   < N_TOK) *(float2*)(o + (m  )*480 + n) = make_float2(a00, a01);
    if (m+1 < N_TOK) *(float2*)(o + (m+1)*480 + n) = make_float2(a10, a11);
    if (m+2 < N_TOK) *(float2*)(o + (m+2)*480 + n) = make_float2(a20, a21);
    if (m+3 < N_TOK) *(float2*)(o + (m+3)*480 + n) = make_float2(a30, a31);
}

// ---------------- K2: attn = Qc^T @ Kc + psi1 partials (120 blocks) ---------
__global__ __launch_bounds__(256) void k_attn(const float* __restrict__ Qc,
                                              const float* __restrict__ Kc,
                                              float* __restrict__ attn,
                                              float* __restrict__ Spart) {
    __shared__ float As[2][16][68];
    __shared__ float Bs[2][16][36];
    __shared__ float red[4][2];
    int tid = threadIdx.x;
    int n0 = blockIdx.x * 32, m0 = blockIdx.y * 64;
    int ty = tid >> 4, tx = tid & 15;
    float a00=0,a01=0,a10=0,a11=0,a20=0,a21=0,a30=0,a31=0;
    const float4 z4 = make_float4(0,0,0,0);
    int kka = tid >> 4, mq = (tid & 15) * 4;
    bool amq = (m0 + mq) < 480;
    const float* aptr = Qc + kka * 480 + m0 + mq;
    bool bact = tid < 128;
    int kk = tid >> 3, nq = (tid & 7) * 4;
    const float* bptr = Kc + kk * 480 + n0 + nq;
    const int NS = 13;
    float4 ra = (amq && kka < N_TOK) ? *(const float4*)(aptr) : z4;
    float4 rb = (bact && kk < N_TOK) ? *(const float4*)(bptr) : z4;
    *(float4*)&As[0][kka][mq] = ra;
    if (bact) *(float4*)&Bs[0][kk][nq] = rb;
    ra = (amq && 16 + kka < N_TOK) ? *(const float4*)(aptr + 16*480) : z4;
    rb = (bact && 16 + kk < N_TOK) ? *(const float4*)(bptr + 16*480) : z4;
    __syncthreads();
    for (int s = 0; s < NS; ++s) {
        int b = s & 1;
        float4 fa = z4, fb = z4;
        if (s + 2 < NS) {
            int k0 = (s + 2) * 16;
            fa = (amq && k0 + kka < N_TOK) ? *(const float4*)(aptr + k0*480) : z4;
            fb = (bact && k0 + kk < N_TOK) ? *(const float4*)(bptr + k0*480) : z4;
        }
        GEMM_COMPUTE(As[b], Bs[b]);
        if (s + 1 < NS) {
            int nb = b ^ 1;
            *(float4*)&As[nb][kka][mq] = ra;
            if (bact) *(float4*)&Bs[nb][kk][nq] = rb;
        }
        __syncthreads();
        ra = fa; rb = fb;
    }
    int m = m0 + ty*4, n = n0 + tx*2;
    if (m   < 480) *(float2*)(attn + (m  )*480 + n) = make_float2(a00, a01);
    if (m+1 < 480) *(float2*)(attn + (m+1)*480 + n) = make_float2(a10, a11);
    if (m+2 < 480) *(float2*)(attn + (m+2)*480 + n) = make_float2(a20, a21);
    if (m+3 < 480) *(float2*)(attn + (m+3)*480 + n) = make_float2(a30, a31);
    float ls = a00+a01+a10+a11+a20+a21+a30+a31;
    float lq = a00*a00+a01*a01+a10*a10+a11*a11+a20*a20+a21*a21+a30*a30+a31*a31;
    #pragma unroll
    for (int o = 32; o > 0; o >>= 1) { ls += __shfl_xor(ls, o, 64); lq += __shfl_xor(lq, o, 64); }
    int wid = tid >> 6, lane = tid & 63;
    if (lane == 0) { red[wid][0] = ls; red[wid][1] = lq; }
    __syncthreads();
    if (tid == 0) {
        int bid = blockIdx.y * gridDim.x + blockIdx.x;
        Spart[bid*2]   = red[0][0] + red[1][0] + red[2][0] + red[3][0];
        Spart[bid*2+1] = red[0][1] + red[1][1] + red[2][1] + red[3][1];
    }
}

// ------- K3: fused softmax + T_hat GEMM + KV projection + kpart (60 blocks) -
__global__ __launch_bounds__(256) void k_thatkv(const float* __restrict__ Vc,
                                                const float* __restrict__ attn,
                                                const float* __restrict__ Spart,
                                                const float* __restrict__ g1,
                                                const float* __restrict__ Wk,
                                                const float* __restrict__ Wv,
                                                float2* __restrict__ KV,
                                                float* __restrict__ kpart) {
    __shared__ float As[2][16][68];
    __shared__ float Bs[2][16][36];
    __shared__ float red[4][16];
    __shared__ float M2s[32], INVs[32];
    __shared__ float Tile[64][33];
    int bid = blockIdx.x;
    int n0 = (bid % 15) * 32, m0 = (bid / 15) * 64;
    int tid = threadIdx.x;
    int wid = tid >> 6, lane = tid & 63;
    // ---- psi1 scale from partials ----
    float ps = 0.f, pq = 0.f;
    if (tid < 120) { ps = Spart[tid*2]; pq = Spart[tid*2+1]; }
    #pragma unroll
    for (int o = 32; o > 0; o >>= 1) { ps += __shfl_xor(ps, o, 64); pq += __shfl_xor(pq, o, 64); }
    if (lane == 0) { red[wid][0] = ps; red[wid][1] = pq; }
    __syncthreads();
    float S  = red[0][0] + red[1][0] + red[2][0] + red[3][0];
    float SQ = red[0][1] + red[1][1] + red[2][1] + red[3][1];
    const float invCC = 1.f / (480.f * 480.f);
    float mean = S * invCC;
    float var  = SQ * invCC - mean * mean;
    float s2 = g1[0] * rsqrtf(var + EPSN) * LOG2E;
    // ---- row stats for this block's 32 rows ----
    int g = tid >> 5, l32 = tid & 31;
    #pragma unroll 1
    for (int batch = 0; batch < 4; ++batch) {
        int r = batch * 8 + g;
        const float* rowp = attn + (n0 + r) * 480 + l32;
        float mx = -INFINITY;
        #pragma unroll
        for (int p = 0; p < 15; ++p) mx = fmaxf(mx, s2 * rowp[p*32]);
        #pragma unroll
        for (int o = 16; o > 0; o >>= 1) mx = fmaxf(mx, __shfl_xor(mx, o, 64));
        if (l32 == 0) M2s[r] = mx;
    }
    __syncthreads();
    #pragma unroll 1
    for (int batch = 0; batch < 4; ++batch) {
        int r = batch * 8 + g;
        const float* rowp = attn + (n0 + r) * 480 + l32;
        float m2 = M2s[r];
        float sm = 0.f;
        #pragma unroll
        for (int p = 0; p < 15; ++p) sm += fast_exp2(fmaf(s2, rowp[p*32], -m2));
        #pragma unroll
        for (int o = 16; o > 0; o >>= 1) sm += __shfl_xor(sm, o, 64);
        if (l32 == 0) INVs[r] = 1.f / sm;
    }
    __syncthreads();
    // ---- double-buffered GEMM: A=Vc, B=softmax(sim) on-the-fly ----
    int ty = tid >> 4, tx = tid & 15;
    float a00=0,a01=0,a10=0,a11=0,a20=0,a21=0,a30=0,a31=0;
    const float4 z4 = make_float4(0,0,0,0);
    int mrow = tid >> 2, kq = (tid & 3) * 4;
    bool am = (m0 + mrow) < N_TOK;
    const float* aptr = Vc + (m0 + mrow) * 480 + kq;
    bool bact = tid < 128;
    int nrow = tid >> 2, bkq = (tid & 3) * 4;
    const float* bptr = attn + (n0 + nrow) * 480 + bkq;
    float nM2r = 0.f, invr = 0.f;
    if (bact) { nM2r = -M2s[nrow]; invr = INVs[nrow]; }
    const int NS = 30;
    float4 ra = am ? *(const float4*)(aptr) : z4;
    float4 rb = bact ? *(const float4*)(bptr) : z4;
    As[0][kq+0][mrow]=ra.x; As[0][kq+1][mrow]=ra.y; As[0][kq+2][mrow]=ra.z; As[0][kq+3][mrow]=ra.w;
    if (bact) {
        Bs[0][bkq+0][nrow] = fast_exp2(fmaf(s2, rb.x, nM2r)) * invr;
        Bs[0][bkq+1][nrow] = fast_exp2(fmaf(s2, rb.y, nM2r)) * invr;
        Bs[0][bkq+2][nrow] = fast_exp2(fmaf(s2, rb.z, nM2r)) * invr;
        Bs[0][bkq+3][nrow] = fast_exp2(fmaf(s2, rb.w, nM2r)) * invr;
    }
    ra = am ? *(const float4*)(aptr + 16) : z4;
    rb = bact ? *(const float4*)(bptr + 16) : z4;
    __syncthreads();
    for (int s = 0; s < NS; ++s) {
        int b = s & 1;
        float4 fa = z4, fb = z4;
        if (s + 2 < NS) {
            fa = am ? *(const float4*)(aptr + (s+2)*16) : z4;
            fb = bact ? *(const float4*)(bptr + (s+2)*16) : z4;
        }
        GEMM_COMPUTE(As[b], Bs[b]);
        if (s + 1 < NS) {
            int nb = b ^ 1;
            As[nb][kq+0][mrow]=ra.x; As[nb][kq+1][mrow]=ra.y; As[nb][kq+2][mrow]=ra.z; As[nb][kq+3][mrow]=ra.w;
            if (bact) {
                Bs[nb][bkq+0][nrow] = fast_exp2(fmaf(s2, rb.x, nM2r)) * invr;
                Bs[nb][bkq+1][nrow] = fast_exp2(fmaf(s2, rb.y, nM2r)) * invr;
                Bs[nb][bkq+2][nrow] = fast_exp2(fmaf(s2, rb.z, nM2r)) * invr;
                Bs[nb][bkq+3][nrow] = fast_exp2(fmaf(s2, rb.w, nM2r)) * invr;
            }
        }
        __syncthreads();
        ra = fa; rb = fb;
    }
    // ---- stage tile, project to K/V, per-block k-stats ----
    int r0 = ty*4, cc = tx*2;
    Tile[r0+0][cc] = a00; Tile[r0+0][cc+1] = a01;
    Tile[r0+1][cc] = a10; Tile[r0+1][cc+1] = a11;
    Tile[r0+2][cc] = a20; Tile[r0+2][cc+1] = a21;
    Tile[r0+3][cc] = a30; Tile[r0+3][cc+1] = a31;
    __syncthreads();
    float su[4] = {0,0,0,0}, sq[4] = {0,0,0,0};
    float mx[4] = {-INFINITY,-INFINITY,-INFINITY,-INFINITY};
    float mn[4] = { INFINITY, INFINITY, INFINITY, INFINITY};
    #pragma unroll
    for (int rep = 0; rep < 2; ++rep) {
        int e = tid + rep * 256;
        int t = e >> 3, jj = e & 7;
        int tok = m0 + t;
        bool act = tok < N_TOK;
        float c0 = Tile[t][4*jj], c1 = Tile[t][4*jj+1];
        float c2 = Tile[t][4*jj+2], c3 = Tile[t][4*jj+3];
        int m_kv = (n0/4 + jj) * 196 + tok;
        #pragma unroll
        for (int h = 0; h < 4; ++h) {
            float kh = c0*Wk[h] + c1*Wk[4+h] + c2*Wk[8+h] + c3*Wk[12+h];
            float vh = c0*Wv[h] + c1*Wv[4+h] + c2*Wv[8+h] + c3*Wv[12+h];
            if (act) {
                KV[h * M_KV + m_kv] = make_float2(kh, vh);
                su[h] += kh; sq[h] += kh * kh;
                mx[h] = fmaxf(mx[h], kh); mn[h] = fminf(mn[h], kh);
            }
        }
    }
    #pragma unroll
    for (int h = 0; h < 4; ++h) {
        #pragma unroll
        for (int o = 32; o > 0; o >>= 1) {
            su[h] += __shfl_xor(su[h], o, 64);
            sq[h] += __shfl_xor(sq[h], o, 64);
            mx[h] = fmaxf(mx[h], __shfl_xor(mx[h], o, 64));
            mn[h] = fminf(mn[h], __shfl_xor(mn[h], o, 64));
        }
        if (lane == 0) {
            red[wid][h*4+0] = su[h]; red[wid][h*4+1] = sq[h];
            red[wid][h*4+2] = mx[h]; red[wid][h*4+3] = mn[h];
        }
    }
    __syncthreads();
    if (tid < 16) {
        int h = tid & 3, st = tid >> 2;
        float v0 = red[0][h*4+st], v1 = red[1][h*4+st], v2 = red[2][h*4+st], v3 = red[3][h*4+st];
        float r;
        if (st < 2)       r = v0 + v1 + v2 + v3;
        else if (st == 2) r = fmaxf(fmaxf(v0, v1), fmaxf(v2, v3));
        else              r = fminf(fminf(v0, v1), fminf(v2, v3));
        kpart[st * 256 + h * 64 + bid] = r;
    }
}

// -------- K4: branch attention, full-K per block, in-block finalize ---------
// grid = 196 blocks x 1024 threads. Wave w: head h = w>>2 over K-quarter p = w&3.
// 16 waves/block = 4 waves/SIMD on active CUs -> trans pipe saturated.
#define QG 49
__global__ __launch_bounds__(1024) void k_branch(
        const float* __restrict__ emb1, const float* __restrict__ emb2,
        const float* __restrict__ emb3, const float* __restrict__ emb4,
        const float* __restrict__ Wq1, const float* __restrict__ Wq2,
        const float* __restrict__ Wq3, const float* __restrict__ Wq4,
        const float* __restrict__ g2v,
        const float2* __restrict__ KV, const float* __restrict__ kpart,
        const float* __restrict__ Wo1, const float* __restrict__ Wo2,
        const float* __restrict__ Wo3, const float* __restrict__ Wo4,
        float* __restrict__ out) {
    __shared__ float lsh[4][4][4];   // [head][quarter][j]
    __shared__ float ash[4][4][4];
    int tid = threadIdx.x;
    int w = tid >> 6, lane = tid & 63;
    int h = w >> 2, p = w & 3;                 // head, K-quarter
    int bid = blockIdx.x;
    int i = bid / QG, qg = bid % QG;
    const float* emb = (i == 0) ? emb1 : (i == 1) ? emb2 : (i == 2) ? emb3 : emb4;
    const float* Wq  = (i == 0) ? Wq1 : (i == 1) ? Wq2 : (i == 2) ? Wq3 : Wq4;
    float wq0 = Wq[h], wq1 = Wq[4+h], wq2 = Wq[8+h], wq3 = Wq[12+h];
    // ---- per-wave psi2 stats for (i, h) (duplicated across the 4 quarters) ----
    float s = 0.f, s2 = 0.f;
    #pragma unroll
    for (int r = 0; r < 4; ++r) {
        int t = lane + r * 64;
        if (t < N_TOK) {
            float Q = emb[t*4]*wq0 + emb[t*4+1]*wq1 + emb[t*4+2]*wq2 + emb[t*4+3]*wq3;
            s += Q; s2 += Q * Q;
        }
    }
    float ks = 0.f, kq2 = 0.f, km = -INFINITY, kn = INFINITY;
    if (lane < 60) {
        ks  = kpart[0*256 + h*64 + lane];
        kq2 = kpart[1*256 + h*64 + lane];
        km  = kpart[2*256 + h*64 + lane];
        kn  = kpart[3*256 + h*64 + lane];
    }
    #pragma unroll
    for (int o = 32; o > 0; o >>= 1) {
        s += __shfl_xor(s, o, 64); s2 += __shfl_xor(s2, o, 64);
        ks += __shfl_xor(ks, o, 64); kq2 += __shfl_xor(kq2, o, 64);
        km = fmaxf(km, __shfl_xor(km, o, 64)); kn = fminf(kn, __shfl_xor(kn, o, 64));
    }
    float Qbar = s * (1.f/196.f), Q2bar = s2 * (1.f/196.f);
    float Kbar = ks * (1.f/(float)M_KV), K2bar = kq2 * (1.f/(float)M_KV);
    float mu = Qbar * Kbar;
    float var = Q2bar * K2bar - mu * mu;
    float sc = g2v[h] * rsqrtf(var + EPSN);
    // ---- 4 q's: beta (log2e folded) + analytic row max ----
    float B2[4], nM2[4];
    #pragma unroll
    for (int j = 0; j < 4; ++j) {
        int q = qg * 4 + j;
        float Qj = emb[q*4]*wq0 + emb[q*4+1]*wq1 + emb[q*4+2]*wq2 + emb[q*4+3]*wq3;
        float b = Qj * sc;
        float M = (b >= 0.f) ? b * km : b * kn;
        B2[j]  = b * LOG2E;
        nM2[j] = -M * LOG2E;
    }
    // ---- K-quarter scan: float4 = 2 keys/lane/load, 4 loads in flight ----
    const float4* kv4 = (const float4*)(KV + h * M_KV);
    const int KQ = M_KV / 8;     // 2940 float4 per quarter
    int kstart = p * KQ, kendq = kstart + KQ;
    float l[4] = {0,0,0,0};
    float a[4] = {0,0,0,0};
#define PROC8(P) { \
        _Pragma("unroll") \
        for (int j = 0; j < 4; ++j) { \
            float x = fast_exp2(fmaf(B2[j], P.x, nM2[j])); \
            l[j] += x; a[j] = fmaf(x, P.y, a[j]); \
            float y = fast_exp2(fmaf(B2[j], P.z, nM2[j])); \
            l[j] += y; a[j] = fmaf(y, P.w, a[j]); \
        } }
    int k4 = kstart + lane;
    for (; k4 + 192 < kendq; k4 += 256) {
        float4 p0 = kv4[k4], p1 = kv4[k4+64], p2 = kv4[k4+128], p3 = kv4[k4+192];
        PROC8(p0); PROC8(p1); PROC8(p2); PROC8(p3);
    }
    for (; k4 < kendq; k4 += 64) { float4 pv = kv4[k4]; PROC8(pv); }
#undef PROC8
    // ---- per-wave reduce -> LDS partials ----
    #pragma unroll
    for (int j = 0; j < 4; ++j) {
        float lv = l[j], av = a[j];
        #pragma unroll
        for (int o = 32; o > 0; o >>= 1) { lv += __shfl_xor(lv, o, 64); av += __shfl_xor(av, o, 64); }
        if (lane == 0) { lsh[h][p][j] = lv; ash[h][p][j] = av; }
    }
    __syncthreads();
    // ---- in-block finalize: out[i, qg*4+j, :] = sum_h c[h][j] * Wo_i[h,:] ----
    if (tid < 4) {
        const float* Wo = (i == 0) ? Wo1 : (i == 1) ? Wo2 : (i == 2) ? Wo3 : Wo4;
        int j = tid;
        float c[4];
        #pragma unroll
        for (int hh = 0; hh < 4; ++hh) {
            float L = lsh[hh][0][j] + lsh[hh][1][j] + lsh[hh][2][j] + lsh[hh][3][j];
            float A = ash[hh][0][j] + ash[hh][1][j] + ash[hh][2][j] + ash[hh][3][j];
            c[hh] = A / L;
        }
        float4 o;
        o.x = c[0]*Wo[0] + c[1]*Wo[4] + c[2]*Wo[8]  + c[3]*Wo[12];
        o.y = c[0]*Wo[1] + c[1]*Wo[5] + c[2]*Wo[9]  + c[3]*Wo[13];
        o.z = c[0]*Wo[2] + c[1]*Wo[6] + c[2]*Wo[10] + c[3]*Wo[14];
        o.w = c[0]*Wo[3] + c[1]*Wo[7] + c[2]*Wo[11] + c[3]*Wo[15];
        *(float4*)(out + i * 784 + (qg * 4 + j) * 4) = o;
    }
}

extern "C" void kernel_launch(void* const* d_in, const int* in_sizes, int n_in,
                              void* d_out, int out_size, void* d_ws, size_t ws_size,
                              hipStream_t stream) {
    const float* emb1 = (const float*)d_in[0];
    const float* emb2 = (const float*)d_in[1];
    const float* emb3 = (const float*)d_in[2];
    const float* emb4 = (const float*)d_in[3];
    const float* embC = (const float*)d_in[4];
    const float* WqC  = (const float*)d_in[5];
    const float* WkC  = (const float*)d_in[6];
    const float* WvC  = (const float*)d_in[7];
    const float* Wq1  = (const float*)d_in[8];
    const float* Wq2  = (const float*)d_in[9];
    const float* Wq3  = (const float*)d_in[10];
    const float* Wq4  = (const float*)d_in[11];
    const float* Wk   = (const float*)d_in[12];
    const float* Wv   = (const float*)d_in[13];
    const float* Wo1  = (const float*)d_in[14];
    const float* Wo2  = (const float*)d_in[15];
    const float* Wo3  = (const float*)d_in[16];
    const float* Wo4  = (const float*)d_in[17];
    const float* g1   = (const float*)d_in[18];
    const float* g2   = (const float*)d_in[20];
    float* ws = (float*)d_ws;
    float* out = (float*)d_out;

    k_qkv<<<180, 256, 0, stream>>>(embC, WqC, WkC, WvC, ws);
    k_attn<<<dim3(15, 8), 256, 0, stream>>>(ws + OFF_QC, ws + OFF_KC,
                                            ws + OFF_ATTN, ws + OFF_SPART);
    k_thatkv<<<60, 256, 0, stream>>>(ws + OFF_VC, ws + OFF_ATTN, ws + OFF_SPART, g1,
                                     Wk, Wv, (float2*)(ws + OFF_KV), ws + OFF_KPART);
    k_branch<<<4 * QG, 1024, 0, stream>>>(emb1, emb2, emb3, emb4,
                                          Wq1, Wq2, Wq3, Wq4, g2,
                                          (const float2*)(ws + OFF_KV), ws + OFF_KPART,
                                          Wo1, Wo2, Wo3, Wo4, out);
}

// Round 11
// 69.960 us; speedup vs baseline: 1.4077x; 1.1274x over previous
//
#include <hip/hip_runtime.h>
#include <hip/hip_bf16.h>
#include <math.h>

// Problem constants
#define N_TOK 196
#define M_KV  23520      // (C/4)*N
#define EPSN  1e-3f
#define LOG2E 1.44269504088896340736f

// Workspace layout (in floats)
#define OFF_QC    0
#define OFF_KC    94080
#define OFF_VC    188160
#define OFF_ATTN  282240   // 480*480 raw attn scores (psi1 pre-norm)
#define OFF_KV    512640   // float2[4*23520] = 188160 floats
#define OFF_SPART 700800   // 120*2 psi1 [sum,sumsq] per-block partials
#define OFF_KPART 701056   // [4 stats][4 heads][64 slots] = 1024 floats

__device__ __forceinline__ float fast_exp2(float x) {
#if __has_builtin(__builtin_amdgcn_exp2f)
    return __builtin_amdgcn_exp2f(x);
#else
    return exp2f(x);
#endif
}

#define GEMM_COMPUTE(AS, BS) \
    _Pragma("unroll") \
    for (int kk2 = 0; kk2 < 16; ++kk2) { \
        float4 av = *(const float4*)&AS[kk2][ty*4]; \
        float2 bv = *(const float2*)&BS[kk2][tx*2]; \
        a00 = fmaf(av.x, bv.x, a00); a01 = fmaf(av.x, bv.y, a01); \
        a10 = fmaf(av.y, bv.x, a10); a11 = fmaf(av.y, bv.y, a11); \
        a20 = fmaf(av.z, bv.x, a20); a21 = fmaf(av.z, bv.y, a21); \
        a30 = fmaf(av.w, bv.x, a30); a31 = fmaf(av.w, bv.y, a31); \
    }

// Combine helper: group1 writes accs to Cmb, group0 adds them into registers.
#define COMBINE_ACCS(CMB) \
    if (kg == 1) { \
        CMB[ty*4+0][tx*2] = a00; CMB[ty*4+0][tx*2+1] = a01; \
        CMB[ty*4+1][tx*2] = a10; CMB[ty*4+1][tx*2+1] = a11; \
        CMB[ty*4+2][tx*2] = a20; CMB[ty*4+2][tx*2+1] = a21; \
        CMB[ty*4+3][tx*2] = a30; CMB[ty*4+3][tx*2+1] = a31; \
    } \
    __syncthreads(); \
    if (kg == 0) { \
        a00 += CMB[ty*4+0][tx*2]; a01 += CMB[ty*4+0][tx*2+1]; \
        a10 += CMB[ty*4+1][tx*2]; a11 += CMB[ty*4+1][tx*2+1]; \
        a20 += CMB[ty*4+2][tx*2]; a21 += CMB[ty*4+2][tx*2+1]; \
        a30 += CMB[ty*4+3][tx*2]; a31 += CMB[ty*4+3][tx*2+1]; \
    }

// ---------------- K1: Qc/Kc/Vc = emb_C @ W  (180 blocks x 512) --------------
// K=480 split 240+240 across two 256-thread groups; 2 waves/SIMD.
__global__ __launch_bounds__(512) void k_qkv(const float* __restrict__ embC,
                                             const float* __restrict__ Wq,
                                             const float* __restrict__ Wk,
                                             const float* __restrict__ Wv,
                                             float* __restrict__ ws) {
    int bid = blockIdx.x;
    int zi = bid / 60, rem = bid % 60;
    int m0 = (rem / 15) * 64, n0 = (rem % 15) * 32;
    const float* W = (zi == 0) ? Wq : (zi == 1 ? Wk : Wv);
    float* o = ws + zi * 94080;
    __shared__ float As[2][2][16][68];   // [kgroup][buf]
    __shared__ float Bs[2][2][16][36];
    __shared__ float Cmb[64][33];
    int tid = threadIdx.x;
    int kg = tid >> 8, t = tid & 255;
    int ty = t >> 4, tx = t & 15;
    float a00=0,a01=0,a10=0,a11=0,a20=0,a21=0,a30=0,a31=0;
    const float4 z4 = make_float4(0,0,0,0);
    int mrow = t >> 2, kq = (t & 3) * 4;
    bool am = (m0 + mrow) < N_TOK;
    const float* aptr = embC + (m0 + mrow) * 480 + kg * 240 + kq;
    bool bact = t < 128;
    int kk = t >> 3, nq = (t & 7) * 4;
    const float* bptr = W + (kg * 240 + kk) * 480 + n0 + nq;
    const int NS = 15;
    float4 ra = am ? *(const float4*)(aptr) : z4;
    float4 rb = bact ? *(const float4*)(bptr) : z4;
    As[kg][0][kq+0][mrow]=ra.x; As[kg][0][kq+1][mrow]=ra.y;
    As[kg][0][kq+2][mrow]=ra.z; As[kg][0][kq+3][mrow]=ra.w;
    if (bact) *(float4*)&Bs[kg][0][kk][nq] = rb;
    ra = am ? *(const float4*)(aptr + 16) : z4;
    rb = bact ? *(const float4*)(bptr + 16*480) : z4;
    __syncthreads();
    for (int s = 0; s < NS; ++s) {
        int b = s & 1;
        float4 fa = z4, fb = z4;
        if (s + 2 < NS) {
            fa = am ? *(const float4*)(aptr + (s+2)*16) : z4;
            fb = bact ? *(const float4*)(bptr + (s+2)*16*480) : z4;
        }
        GEMM_COMPUTE(As[kg][b], Bs[kg][b]);
        if (s + 1 < NS) {
            int nb = b ^ 1;
            As[kg][nb][kq+0][mrow]=ra.x; As[kg][nb][kq+1][mrow]=ra.y;
            As[kg][nb][kq+2][mrow]=ra.z; As[kg][nb][kq+3][mrow]=ra.w;
            if (bact) *(float4*)&Bs[kg][nb][kk][nq] = rb;
        }
        __syncthreads();
        ra = fa; rb = fb;
    }
    COMBINE_ACCS(Cmb);
    if (kg == 0) {
        int m = m0 + ty*4, n = n0 + tx*2;
        if (m   < N_TOK) *(float2*)(o + (m  )*480 + n) = make_float2(a00, a01);
        if (m+1 < N_TOK) *(float2*)(o + (m+1)*480 + n) = make_float2(a10, a11);
        if (m+2 < N_TOK) *(float2*)(o + (m+2)*480 + n) = make_float2(a20, a21);
        if (m+3 < N_TOK) *(float2*)(o + (m+3)*480 + n) = make_float2(a30, a31);
    }
}

// ---------------- K2: attn = Qc^T @ Kc + psi1 partials (120 blocks x 512) ---
// K=196 split 112+112 (zero-fill beyond 196). Phantom m-rows zero-filled
// (they feed psi1 stats!) and store-guarded.
__global__ __launch_bounds__(512) void k_attn(const float* __restrict__ Qc,
                                              const float* __restrict__ Kc,
                                              float* __restrict__ attn,
                                              float* __restrict__ Spart) {
    __shared__ float As[2][2][16][68];
    __shared__ float Bs[2][2][16][36];
    __shared__ float Cmb[64][33];
    __shared__ float red[8][2];
    int tid = threadIdx.x;
    int kg = tid >> 8, t = tid & 255;
    int n0 = blockIdx.x * 32, m0 = blockIdx.y * 64;
    int ty = t >> 4, tx = t & 15;
    float a00=0,a01=0,a10=0,a11=0,a20=0,a21=0,a30=0,a31=0;
    const float4 z4 = make_float4(0,0,0,0);
    int kka = t >> 4, mq = (t & 15) * 4;
    bool amq = (m0 + mq) < 480;
    int kbase = kg * 112;
    const float* aptr = Qc + (kbase + kka) * 480 + m0 + mq;
    bool bact = t < 128;
    int kk = t >> 3, nq = (t & 7) * 4;
    const float* bptr = Kc + (kbase + kk) * 480 + n0 + nq;
    const int NS = 7;   // 7*16 = 112 per group
    float4 ra = (amq && kbase + kka < N_TOK) ? *(const float4*)(aptr) : z4;
    float4 rb = (bact && kbase + kk < N_TOK) ? *(const float4*)(bptr) : z4;
    *(float4*)&As[kg][0][kka][mq] = ra;
    if (bact) *(float4*)&Bs[kg][0][kk][nq] = rb;
    ra = (amq && kbase + 16 + kka < N_TOK) ? *(const float4*)(aptr + 16*480) : z4;
    rb = (bact && kbase + 16 + kk < N_TOK) ? *(const float4*)(bptr + 16*480) : z4;
    __syncthreads();
    for (int s = 0; s < NS; ++s) {
        int b = s & 1;
        float4 fa = z4, fb = z4;
        if (s + 2 < NS) {
            int k0 = kbase + (s + 2) * 16;
            fa = (amq && k0 + kka < N_TOK) ? *(const float4*)(aptr + (s+2)*16*480) : z4;
            fb = (bact && k0 + kk < N_TOK) ? *(const float4*)(bptr + (s+2)*16*480) : z4;
        }
        GEMM_COMPUTE(As[kg][b], Bs[kg][b]);
        if (s + 1 < NS) {
            int nb = b ^ 1;
            *(float4*)&As[kg][nb][kka][mq] = ra;
            if (bact) *(float4*)&Bs[kg][nb][kk][nq] = rb;
        }
        __syncthreads();
        ra = fa; rb = fb;
    }
    COMBINE_ACCS(Cmb);
    float ls = 0.f, lq = 0.f;
    if (kg == 0) {
        int m = m0 + ty*4, n = n0 + tx*2;
        if (m   < 480) *(float2*)(attn + (m  )*480 + n) = make_float2(a00, a01);
        if (m+1 < 480) *(float2*)(attn + (m+1)*480 + n) = make_float2(a10, a11);
        if (m+2 < 480) *(float2*)(attn + (m+2)*480 + n) = make_float2(a20, a21);
        if (m+3 < 480) *(float2*)(attn + (m+3)*480 + n) = make_float2(a30, a31);
        ls = a00+a01+a10+a11+a20+a21+a30+a31;
        lq = a00*a00+a01*a01+a10*a10+a11*a11+a20*a20+a21*a21+a30*a30+a31*a31;
    }
    #pragma unroll
    for (int o = 32; o > 0; o >>= 1) { ls += __shfl_xor(ls, o, 64); lq += __shfl_xor(lq, o, 64); }
    int wid = tid >> 6, lane = tid & 63;
    if (lane == 0) { red[wid][0] = ls; red[wid][1] = lq; }
    __syncthreads();
    if (tid == 0) {
        int bid = blockIdx.y * gridDim.x + blockIdx.x;
        Spart[bid*2]   = red[0][0] + red[1][0] + red[2][0] + red[3][0];
        Spart[bid*2+1] = red[0][1] + red[1][1] + red[2][1] + red[3][1];
    }
}

// ------- K3: softmax + T_hat GEMM + KV projection + kpart (60 blocks x 512) -
__global__ __launch_bounds__(512) void k_thatkv(const float* __restrict__ Vc,
                                                const float* __restrict__ attn,
                                                const float* __restrict__ Spart,
                                                const float* __restrict__ g1,
                                                const float* __restrict__ Wk,
                                                const float* __restrict__ Wv,
                                                float2* __restrict__ KV,
                                                float* __restrict__ kpart) {
    __shared__ float As[2][2][16][68];
    __shared__ float Bs[2][2][16][36];
    __shared__ float red[8][16];
    __shared__ float M2s[32], INVs[32];
    __shared__ float Tile[64][33];
    int bid = blockIdx.x;
    int n0 = (bid % 15) * 32, m0 = (bid / 15) * 64;
    int tid = threadIdx.x;
    int kg = tid >> 8, t = tid & 255;
    int wid = tid >> 6, lane = tid & 63;
    // ---- psi1 scale from partials (waves >=2 contribute zeros) ----
    float ps = 0.f, pq = 0.f;
    if (tid < 120) { ps = Spart[tid*2]; pq = Spart[tid*2+1]; }
    #pragma unroll
    for (int o = 32; o > 0; o >>= 1) { ps += __shfl_xor(ps, o, 64); pq += __shfl_xor(pq, o, 64); }
    if (lane == 0) { red[wid][0] = ps; red[wid][1] = pq; }
    __syncthreads();
    float S = 0.f, SQ = 0.f;
    #pragma unroll
    for (int w = 0; w < 8; ++w) { S += red[w][0]; SQ += red[w][1]; }
    const float invCC = 1.f / (480.f * 480.f);
    float mean = S * invCC;
    float var  = SQ * invCC - mean * mean;
    float s2 = g1[0] * rsqrtf(var + EPSN) * LOG2E;
    // ---- row stats: 16 rows in flight (32-lane group per row) ----
    int g = tid >> 5, l32 = tid & 31;
    #pragma unroll 1
    for (int batch = 0; batch < 2; ++batch) {
        int r = batch * 16 + g;
        const float* rowp = attn + (n0 + r) * 480 + l32;
        float mx = -INFINITY;
        #pragma unroll
        for (int p = 0; p < 15; ++p) mx = fmaxf(mx, s2 * rowp[p*32]);
        #pragma unroll
        for (int o = 16; o > 0; o >>= 1) mx = fmaxf(mx, __shfl_xor(mx, o, 64));
        if (l32 == 0) M2s[r] = mx;
    }
    __syncthreads();
    #pragma unroll 1
    for (int batch = 0; batch < 2; ++batch) {
        int r = batch * 16 + g;
        const float* rowp = attn + (n0 + r) * 480 + l32;
        float m2 = M2s[r];
        float sm = 0.f;
        #pragma unroll
        for (int p = 0; p < 15; ++p) sm += fast_exp2(fmaf(s2, rowp[p*32], -m2));
        #pragma unroll
        for (int o = 16; o > 0; o >>= 1) sm += __shfl_xor(sm, o, 64);
        if (l32 == 0) INVs[r] = 1.f / sm;
    }
    __syncthreads();
    // ---- K-split double-buffered GEMM: A=Vc, B=softmax(sim) on-the-fly ----
    int ty = t >> 4, tx = t & 15;
    float a00=0,a01=0,a10=0,a11=0,a20=0,a21=0,a30=0,a31=0;
    const float4 z4 = make_float4(0,0,0,0);
    int mrow = t >> 2, kq = (t & 3) * 4;
    bool am = (m0 + mrow) < N_TOK;
    const float* aptr = Vc + (m0 + mrow) * 480 + kg * 240 + kq;
    bool bact = t < 128;
    int nrow = t >> 2, bkq = (t & 3) * 4;
    const float* bptr = attn + (n0 + nrow) * 480 + kg * 240 + bkq;
    float nM2r = 0.f, invr = 0.f;
    if (bact) { nM2r = -M2s[nrow]; invr = INVs[nrow]; }
    const int NS = 15;
    float4 ra = am ? *(const float4*)(aptr) : z4;
    float4 rb = bact ? *(const float4*)(bptr) : z4;
    As[kg][0][kq+0][mrow]=ra.x; As[kg][0][kq+1][mrow]=ra.y;
    As[kg][0][kq+2][mrow]=ra.z; As[kg][0][kq+3][mrow]=ra.w;
    if (bact) {
        Bs[kg][0][bkq+0][nrow] = fast_exp2(fmaf(s2, rb.x, nM2r)) * invr;
        Bs[kg][0][bkq+1][nrow] = fast_exp2(fmaf(s2, rb.y, nM2r)) * invr;
        Bs[kg][0][bkq+2][nrow] = fast_exp2(fmaf(s2, rb.z, nM2r)) * invr;
        Bs[kg][0][bkq+3][nrow] = fast_exp2(fmaf(s2, rb.w, nM2r)) * invr;
    }
    ra = am ? *(const float4*)(aptr + 16) : z4;
    rb = bact ? *(const float4*)(bptr + 16) : z4;
    __syncthreads();
    for (int s = 0; s < NS; ++s) {
        int b = s & 1;
        float4 fa = z4, fb = z4;
        if (s + 2 < NS) {
            fa = am ? *(const float4*)(aptr + (s+2)*16) : z4;
            fb = bact ? *(const float4*)(bptr + (s+2)*16) : z4;
        }
        GEMM_COMPUTE(As[kg][b], Bs[kg][b]);
        if (s + 1 < NS) {
            int nb = b ^ 1;
            As[kg][nb][kq+0][mrow]=ra.x; As[kg][nb][kq+1][mrow]=ra.y;
            As[kg][nb][kq+2][mrow]=ra.z; As[kg][nb][kq+3][mrow]=ra.w;
            if (bact) {
                Bs[kg][nb][bkq+0][nrow] = fast_exp2(fmaf(s2, rb.x, nM2r)) * invr;
                Bs[kg][nb][bkq+1][nrow] = fast_exp2(fmaf(s2, rb.y, nM2r)) * invr;
                Bs[kg][nb][bkq+2][nrow] = fast_exp2(fmaf(s2, rb.z, nM2r)) * invr;
                Bs[kg][nb][bkq+3][nrow] = fast_exp2(fmaf(s2, rb.w, nM2r)) * invr;
            }
        }
        __syncthreads();
        ra = fa; rb = fb;
    }
    // ---- combine halves into Tile (full That tile) ----
    int r0 = ty*4, cc = tx*2;
    if (kg == 1) {
        Tile[r0+0][cc] = a00; Tile[r0+0][cc+1] = a01;
        Tile[r0+1][cc] = a10; Tile[r0+1][cc+1] = a11;
        Tile[r0+2][cc] = a20; Tile[r0+2][cc+1] = a21;
        Tile[r0+3][cc] = a30; Tile[r0+3][cc+1] = a31;
    }
    __syncthreads();
    if (kg == 0) {
        Tile[r0+0][cc] += a00; Tile[r0+0][cc+1] += a01;
        Tile[r0+1][cc] += a10; Tile[r0+1][cc+1] += a11;
        Tile[r0+2][cc] += a20; Tile[r0+2][cc+1] += a21;
        Tile[r0+3][cc] += a30; Tile[r0+3][cc+1] += a31;
    }
    __syncthreads();
    // ---- K/V projection + per-block k-stats (512 threads, 1 pass) ----
    float su[4] = {0,0,0,0}, sq[4] = {0,0,0,0};
    float mx[4] = {-INFINITY,-INFINITY,-INFINITY,-INFINITY};
    float mn[4] = { INFINITY, INFINITY, INFINITY, INFINITY};
    {
        int e = tid;
        int tr = e >> 3, jj = e & 7;
        int tok = m0 + tr;
        bool act = tok < N_TOK;
        float c0 = Tile[tr][4*jj], c1 = Tile[tr][4*jj+1];
        float c2 = Tile[tr][4*jj+2], c3 = Tile[tr][4*jj+3];
        int m_kv = (n0/4 + jj) * 196 + tok;
        #pragma unroll
        for (int h = 0; h < 4; ++h) {
            float kh = c0*Wk[h] + c1*Wk[4+h] + c2*Wk[8+h] + c3*Wk[12+h];
            float vh = c0*Wv[h] + c1*Wv[4+h] + c2*Wv[8+h] + c3*Wv[12+h];
            if (act) {
                KV[h * M_KV + m_kv] = make_float2(kh, vh);
                su[h] += kh; sq[h] += kh * kh;
                mx[h] = fmaxf(mx[h], kh); mn[h] = fminf(mn[h], kh);
            }
        }
    }
    __syncthreads();   // Tile reads done (red overlays nothing, but keep order)
    #pragma unroll
    for (int h = 0; h < 4; ++h) {
        #pragma unroll
        for (int o = 32; o > 0; o >>= 1) {
            su[h] += __shfl_xor(su[h], o, 64);
            sq[h] += __shfl_xor(sq[h], o, 64);
            mx[h] = fmaxf(mx[h], __shfl_xor(mx[h], o, 64));
            mn[h] = fminf(mn[h], __shfl_xor(mn[h], o, 64));
        }
        if (lane == 0) {
            red[wid][h*4+0] = su[h]; red[wid][h*4+1] = sq[h];
            red[wid][h*4+2] = mx[h]; red[wid][h*4+3] = mn[h];
        }
    }
    __syncthreads();
    if (tid < 16) {
        int h = tid & 3, st = tid >> 2;
        float r;
        if (st < 2) {
            r = 0.f;
            #pragma unroll
            for (int w = 0; w < 8; ++w) r += red[w][h*4+st];
        } else if (st == 2) {
            r = -INFINITY;
            #pragma unroll
            for (int w = 0; w < 8; ++w) r = fmaxf(r, red[w][h*4+st]);
        } else {
            r = INFINITY;
            #pragma unroll
            for (int w = 0; w < 8; ++w) r = fminf(r, red[w][h*4+st]);
        }
        kpart[st * 256 + h * 64 + bid] = r;
    }
}

// -------- K4: branch attention, full-K per block, in-block finalize ---------
// grid = 196 blocks x 1024 threads. Wave w: head h = w>>2 over K-quarter p = w&3.
#define QG 49
__global__ __launch_bounds__(1024) void k_branch(
        const float* __restrict__ emb1, const float* __restrict__ emb2,
        const float* __restrict__ emb3, const float* __restrict__ emb4,
        const float* __restrict__ Wq1, const float* __restrict__ Wq2,
        const float* __restrict__ Wq3, const float* __restrict__ Wq4,
        const float* __restrict__ g2v,
        const float2* __restrict__ KV, const float* __restrict__ kpart,
        const float* __restrict__ Wo1, const float* __restrict__ Wo2,
        const float* __restrict__ Wo3, const float* __restrict__ Wo4,
        float* __restrict__ out) {
    __shared__ float lsh[4][4][4];   // [head][quarter][j]
    __shared__ float ash[4][4][4];
    int tid = threadIdx.x;
    int w = tid >> 6, lane = tid & 63;
    int h = w >> 2, p = w & 3;                 // head, K-quarter
    int bid = blockIdx.x;
    int i = bid / QG, qg = bid % QG;
    const float* emb = (i == 0) ? emb1 : (i == 1) ? emb2 : (i == 2) ? emb3 : emb4;
    const float* Wq  = (i == 0) ? Wq1 : (i == 1) ? Wq2 : (i == 2) ? Wq3 : Wq4;
    float wq0 = Wq[h], wq1 = Wq[4+h], wq2 = Wq[8+h], wq3 = Wq[12+h];
    // ---- per-wave psi2 stats for (i, h) (duplicated across quarters) ----
    float s = 0.f, s2 = 0.f;
    #pragma unroll
    for (int r = 0; r < 4; ++r) {
        int t = lane + r * 64;
        if (t < N_TOK) {
            float Q = emb[t*4]*wq0 + emb[t*4+1]*wq1 + emb[t*4+2]*wq2 + emb[t*4+3]*wq3;
            s += Q; s2 += Q * Q;
        }
    }
    float ks = 0.f, kq2 = 0.f, km = -INFINITY, kn = INFINITY;
    if (lane < 60) {
        ks  = kpart[0*256 + h*64 + lane];
        kq2 = kpart[1*256 + h*64 + lane];
        km  = kpart[2*256 + h*64 + lane];
        kn  = kpart[3*256 + h*64 + lane];
    }
    #pragma unroll
    for (int o = 32; o > 0; o >>= 1) {
        s += __shfl_xor(s, o, 64); s2 += __shfl_xor(s2, o, 64);
        ks += __shfl_xor(ks, o, 64); kq2 += __shfl_xor(kq2, o, 64);
        km = fmaxf(km, __shfl_xor(km, o, 64)); kn = fminf(kn, __shfl_xor(kn, o, 64));
    }
    float Qbar = s * (1.f/196.f), Q2bar = s2 * (1.f/196.f);
    float Kbar = ks * (1.f/(float)M_KV), K2bar = kq2 * (1.f/(float)M_KV);
    float mu = Qbar * Kbar;
    float var = Q2bar * K2bar - mu * mu;
    float sc = g2v[h] * rsqrtf(var + EPSN);
    // ---- 4 q's: beta (log2e folded) + analytic row max ----
    float B2[4], nM2[4];
    #pragma unroll
    for (int j = 0; j < 4; ++j) {
        int q = qg * 4 + j;
        float Qj = emb[q*4]*wq0 + emb[q*4+1]*wq1 + emb[q*4+2]*wq2 + emb[q*4+3]*wq3;
        float b = Qj * sc;
        float M = (b >= 0.f) ? b * km : b * kn;
        B2[j]  = b * LOG2E;
        nM2[j] = -M * LOG2E;
    }
    // ---- K-quarter scan: float4 = 2 keys/lane/load, 4 loads in flight ----
    const float4* kv4 = (const float4*)(KV + h * M_KV);
    const int KQ = M_KV / 8;     // 2940 float4 per quarter
    int kstart = p * KQ, kendq = kstart + KQ;
    float l[4] = {0,0,0,0};
    float a[4] = {0,0,0,0};
#define PROC8(P) { \
        _Pragma("unroll") \
        for (int j = 0; j < 4; ++j) { \
            float x = fast_exp2(fmaf(B2[j], P.x, nM2[j])); \
            l[j] += x; a[j] = fmaf(x, P.y, a[j]); \
            float y = fast_exp2(fmaf(B2[j], P.z, nM2[j])); \
            l[j] += y; a[j] = fmaf(y, P.w, a[j]); \
        } }
    int k4 = kstart + lane;
    for (; k4 + 192 < kendq; k4 += 256) {
        float4 p0 = kv4[k4], p1 = kv4[k4+64], p2 = kv4[k4+128], p3 = kv4[k4+192];
        PROC8(p0); PROC8(p1); PROC8(p2); PROC8(p3);
    }
    for (; k4 < kendq; k4 += 64) { float4 pv = kv4[k4]; PROC8(pv); }
#undef PROC8
    // ---- per-wave reduce -> LDS partials ----
    #pragma unroll
    for (int j = 0; j < 4; ++j) {
        float lv = l[j], av = a[j];
        #pragma unroll
        for (int o = 32; o > 0; o >>= 1) { lv += __shfl_xor(lv, o, 64); av += __shfl_xor(av, o, 64); }
        if (lane == 0) { lsh[h][p][j] = lv; ash[h][p][j] = av; }
    }
    __syncthreads();
    // ---- in-block finalize ----
    if (tid < 4) {
        const float* Wo = (i == 0) ? Wo1 : (i == 1) ? Wo2 : (i == 2) ? Wo3 : Wo4;
        int j = tid;
        float c[4];
        #pragma unroll
        for (int hh = 0; hh < 4; ++hh) {
            float L = lsh[hh][0][j] + lsh[hh][1][j] + lsh[hh][2][j] + lsh[hh][3][j];
            float A = ash[hh][0][j] + ash[hh][1][j] + ash[hh][2][j] + ash[hh][3][j];
            c[hh] = A / L;
        }
        float4 o;
        o.x = c[0]*Wo[0] + c[1]*Wo[4] + c[2]*Wo[8]  + c[3]*Wo[12];
        o.y = c[0]*Wo[1] + c[1]*Wo[5] + c[2]*Wo[9]  + c[3]*Wo[13];
        o.z = c[0]*Wo[2] + c[1]*Wo[6] + c[2]*Wo[10] + c[3]*Wo[14];
        o.w = c[0]*Wo[3] + c[1]*Wo[7] + c[2]*Wo[11] + c[3]*Wo[15];
        *(float4*)(out + i * 784 + (qg * 4 + j) * 4) = o;
    }
}

extern "C" void kernel_launch(void* const* d_in, const int* in_sizes, int n_in,
                              void* d_out, int out_size, void* d_ws, size_t ws_size,
                              hipStream_t stream) {
    const float* emb1 = (const float*)d_in[0];
    const float* emb2 = (const float*)d_in[1];
    const float* emb3 = (const float*)d_in[2];
    const float* emb4 = (const float*)d_in[3];
    const float* embC = (const float*)d_in[4];
    const float* WqC  = (const float*)d_in[5];
    const float* WkC  = (const float*)d_in[6];
    const float* WvC  = (const float*)d_in[7];
    const float* Wq1  = (const float*)d_in[8];
    const float* Wq2  = (const float*)d_in[9];
    const float* Wq3  = (const float*)d_in[10];
    const float* Wq4  = (const float*)d_in[11];
    const float* Wk   = (const float*)d_in[12];
    const float* Wv   = (const float*)d_in[13];
    const float* Wo1  = (const float*)d_in[14];
    const float* Wo2  = (const float*)d_in[15];
    const float* Wo3  = (const float*)d_in[16];
    const float* Wo4  = (const float*)d_in[17];
    const float* g1   = (const float*)d_in[18];
    const float* g2   = (const float*)d_in[20];
    float* ws = (float*)d_ws;
    float* out = (float*)d_out;

    k_qkv<<<180, 512, 0, stream>>>(embC, WqC, WkC, WvC, ws);
    k_attn<<<dim3(15, 8), 512, 0, stream>>>(ws + OFF_QC, ws + OFF_KC,
                                            ws + OFF_ATTN, ws + OFF_SPART);
    k_thatkv<<<60, 512, 0, stream>>>(ws + OFF_VC, ws + OFF_ATTN, ws + OFF_SPART, g1,
                                     Wk, Wv, (float2*)(ws + OFF_KV), ws + OFF_KPART);
    k_branch<<<4 * QG, 1024, 0, stream>>>(emb1, emb2, emb3, emb4,
                                          Wq1, Wq2, Wq3, Wq4, g2,
                                          (const float2*)(ws + OFF_KV), ws + OFF_KPART,
                                          Wo1, Wo2, Wo3, Wo4, out);
}

// Round 12
// 64.868 us; speedup vs baseline: 1.5182x; 1.0785x over previous
//
#include <hip/hip_runtime.h>
#include <hip/hip_bf16.h>
#include <math.h>

// Problem constants
#define N_TOK 196
#define M_KV  23520      // (C/4)*N
#define EPSN  1e-3f
#define LOG2E 1.44269504088896340736f

// Workspace layout (in floats)
#define OFF_QC    0
#define OFF_KC    94080
#define OFF_VC    188160
#define OFF_ATTN  282240   // 480*480 raw attn scores (psi1 pre-norm)
#define OFF_KV    512640   // float2[4*23520] = 188160 floats
#define OFF_SPART 700800   // 120*2 psi1 [sum,sumsq] per-block partials
#define OFF_KPART 701056   // [2 stats][4 heads][64 slots] (stride kept 256/stat)

__device__ __forceinline__ float fast_exp2(float x) {
#if __has_builtin(__builtin_amdgcn_exp2f)
    return __builtin_amdgcn_exp2f(x);
#else
    return exp2f(x);
#endif
}

#define GEMM_COMPUTE(AS, BS) \
    _Pragma("unroll") \
    for (int kk2 = 0; kk2 < 16; ++kk2) { \
        float4 av = *(const float4*)&AS[kk2][ty*4]; \
        float2 bv = *(const float2*)&BS[kk2][tx*2]; \
        a00 = fmaf(av.x, bv.x, a00); a01 = fmaf(av.x, bv.y, a01); \
        a10 = fmaf(av.y, bv.x, a10); a11 = fmaf(av.y, bv.y, a11); \
        a20 = fmaf(av.z, bv.x, a20); a21 = fmaf(av.z, bv.y, a21); \
        a30 = fmaf(av.w, bv.x, a30); a31 = fmaf(av.w, bv.y, a31); \
    }

// Combine helper: group1 writes accs to Cmb, group0 adds them into registers.
#define COMBINE_ACCS(CMB) \
    if (kg == 1) { \
        CMB[ty*4+0][tx*2] = a00; CMB[ty*4+0][tx*2+1] = a01; \
        CMB[ty*4+1][tx*2] = a10; CMB[ty*4+1][tx*2+1] = a11; \
        CMB[ty*4+2][tx*2] = a20; CMB[ty*4+2][tx*2+1] = a21; \
        CMB[ty*4+3][tx*2] = a30; CMB[ty*4+3][tx*2+1] = a31; \
    } \
    __syncthreads(); \
    if (kg == 0) { \
        a00 += CMB[ty*4+0][tx*2]; a01 += CMB[ty*4+0][tx*2+1]; \
        a10 += CMB[ty*4+1][tx*2]; a11 += CMB[ty*4+1][tx*2+1]; \
        a20 += CMB[ty*4+2][tx*2]; a21 += CMB[ty*4+2][tx*2+1]; \
        a30 += CMB[ty*4+3][tx*2]; a31 += CMB[ty*4+3][tx*2+1]; \
    }

// ---------------- K1: Qc/Kc/Vc = emb_C @ W  (180 blocks x 512) --------------
__global__ __launch_bounds__(512) void k_qkv(const float* __restrict__ embC,
                                             const float* __restrict__ Wq,
                                             const float* __restrict__ Wk,
                                             const float* __restrict__ Wv,
                                             float* __restrict__ ws) {
    int bid = blockIdx.x;
    int zi = bid / 60, rem = bid % 60;
    int m0 = (rem / 15) * 64, n0 = (rem % 15) * 32;
    const float* W = (zi == 0) ? Wq : (zi == 1 ? Wk : Wv);
    float* o = ws + zi * 94080;
    __shared__ float As[2][2][16][68];   // [kgroup][buf]
    __shared__ float Bs[2][2][16][36];
    __shared__ float Cmb[64][33];
    int tid = threadIdx.x;
    int kg = tid >> 8, t = tid & 255;
    int ty = t >> 4, tx = t & 15;
    float a00=0,a01=0,a10=0,a11=0,a20=0,a21=0,a30=0,a31=0;
    const float4 z4 = make_float4(0,0,0,0);
    int mrow = t >> 2, kq = (t & 3) * 4;
    bool am = (m0 + mrow) < N_TOK;
    const float* aptr = embC + (m0 + mrow) * 480 + kg * 240 + kq;
    bool bact = t < 128;
    int kk = t >> 3, nq = (t & 7) * 4;
    const float* bptr = W + (kg * 240 + kk) * 480 + n0 + nq;
    const int NS = 15;
    float4 ra = am ? *(const float4*)(aptr) : z4;
    float4 rb = bact ? *(const float4*)(bptr) : z4;
    As[kg][0][kq+0][mrow]=ra.x; As[kg][0][kq+1][mrow]=ra.y;
    As[kg][0][kq+2][mrow]=ra.z; As[kg][0][kq+3][mrow]=ra.w;
    if (bact) *(float4*)&Bs[kg][0][kk][nq] = rb;
    ra = am ? *(const float4*)(aptr + 16) : z4;
    rb = bact ? *(const float4*)(bptr + 16*480) : z4;
    __syncthreads();
    for (int s = 0; s < NS; ++s) {
        int b = s & 1;
        float4 fa = z4, fb = z4;
        if (s + 2 < NS) {
            fa = am ? *(const float4*)(aptr + (s+2)*16) : z4;
            fb = bact ? *(const float4*)(bptr + (s+2)*16*480) : z4;
        }
        GEMM_COMPUTE(As[kg][b], Bs[kg][b]);
        if (s + 1 < NS) {
            int nb = b ^ 1;
            As[kg][nb][kq+0][mrow]=ra.x; As[kg][nb][kq+1][mrow]=ra.y;
            As[kg][nb][kq+2][mrow]=ra.z; As[kg][nb][kq+3][mrow]=ra.w;
            if (bact) *(float4*)&Bs[kg][nb][kk][nq] = rb;
        }
        __syncthreads();
        ra = fa; rb = fb;
    }
    COMBINE_ACCS(Cmb);
    if (kg == 0) {
        int m = m0 + ty*4, n = n0 + tx*2;
        if (m   < N_TOK) *(float2*)(o + (m  )*480 + n) = make_float2(a00, a01);
        if (m+1 < N_TOK) *(float2*)(o + (m+1)*480 + n) = make_float2(a10, a11);
        if (m+2 < N_TOK) *(float2*)(o + (m+2)*480 + n) = make_float2(a20, a21);
        if (m+3 < N_TOK) *(float2*)(o + (m+3)*480 + n) = make_float2(a30, a31);
    }
}

// ---------------- K2: attn = Qc^T @ Kc + psi1 partials (120 blocks x 512) ---
__global__ __launch_bounds__(512) void k_attn(const float* __restrict__ Qc,
                                              const float* __restrict__ Kc,
                                              float* __restrict__ attn,
                                              float* __restrict__ Spart) {
    __shared__ float As[2][2][16][68];
    __shared__ float Bs[2][2][16][36];
    __shared__ float Cmb[64][33];
    __shared__ float red[8][2];
    int tid = threadIdx.x;
    int kg = tid >> 8, t = tid & 255;
    int n0 = blockIdx.x * 32, m0 = blockIdx.y * 64;
    int ty = t >> 4, tx = t & 15;
    float a00=0,a01=0,a10=0,a11=0,a20=0,a21=0,a30=0,a31=0;
    const float4 z4 = make_float4(0,0,0,0);
    int kka = t >> 4, mq = (t & 15) * 4;
    bool amq = (m0 + mq) < 480;
    int kbase = kg * 112;
    const float* aptr = Qc + (kbase + kka) * 480 + m0 + mq;
    bool bact = t < 128;
    int kk = t >> 3, nq = (t & 7) * 4;
    const float* bptr = Kc + (kbase + kk) * 480 + n0 + nq;
    const int NS = 7;   // 7*16 = 112 per group
    float4 ra = (amq && kbase + kka < N_TOK) ? *(const float4*)(aptr) : z4;
    float4 rb = (bact && kbase + kk < N_TOK) ? *(const float4*)(bptr) : z4;
    *(float4*)&As[kg][0][kka][mq] = ra;
    if (bact) *(float4*)&Bs[kg][0][kk][nq] = rb;
    ra = (amq && kbase + 16 + kka < N_TOK) ? *(const float4*)(aptr + 16*480) : z4;
    rb = (bact && kbase + 16 + kk < N_TOK) ? *(const float4*)(bptr + 16*480) : z4;
    __syncthreads();
    for (int s = 0; s < NS; ++s) {
        int b = s & 1;
        float4 fa = z4, fb = z4;
        if (s + 2 < NS) {
            int k0 = kbase + (s + 2) * 16;
            fa = (amq && k0 + kka < N_TOK) ? *(const float4*)(aptr + (s+2)*16*480) : z4;
            fb = (bact && k0 + kk < N_TOK) ? *(const float4*)(bptr + (s+2)*16*480) : z4;
        }
        GEMM_COMPUTE(As[kg][b], Bs[kg][b]);
        if (s + 1 < NS) {
            int nb = b ^ 1;
            *(float4*)&As[kg][nb][kka][mq] = ra;
            if (bact) *(float4*)&Bs[kg][nb][kk][nq] = rb;
        }
        __syncthreads();
        ra = fa; rb = fb;
    }
    COMBINE_ACCS(Cmb);
    float ls = 0.f, lq = 0.f;
    if (kg == 0) {
        int m = m0 + ty*4, n = n0 + tx*2;
        if (m   < 480) *(float2*)(attn + (m  )*480 + n) = make_float2(a00, a01);
        if (m+1 < 480) *(float2*)(attn + (m+1)*480 + n) = make_float2(a10, a11);
        if (m+2 < 480) *(float2*)(attn + (m+2)*480 + n) = make_float2(a20, a21);
        if (m+3 < 480) *(float2*)(attn + (m+3)*480 + n) = make_float2(a30, a31);
        ls = a00+a01+a10+a11+a20+a21+a30+a31;
        lq = a00*a00+a01*a01+a10*a10+a11*a11+a20*a20+a21*a21+a30*a30+a31*a31;
    }
    #pragma unroll
    for (int o = 32; o > 0; o >>= 1) { ls += __shfl_xor(ls, o, 64); lq += __shfl_xor(lq, o, 64); }
    int wid = tid >> 6, lane = tid & 63;
    if (lane == 0) { red[wid][0] = ls; red[wid][1] = lq; }
    __syncthreads();
    if (tid == 0) {
        int bid = blockIdx.y * gridDim.x + blockIdx.x;
        Spart[bid*2]   = red[0][0] + red[1][0] + red[2][0] + red[3][0];
        Spart[bid*2+1] = red[0][1] + red[1][1] + red[2][1] + red[3][1];
    }
}

// ------- K3: softmax + T_hat GEMM + KV projection + kpart (60 blocks x 512) -
// Deferred normalization: B = exp2(s2*raw) unshifted (exponent |.| << 126);
// column sums accumulated during staging; tile scaled by 1/colsum at combine.
__global__ __launch_bounds__(512) void k_thatkv(const float* __restrict__ Vc,
                                                const float* __restrict__ attn,
                                                const float* __restrict__ Spart,
                                                const float* __restrict__ g1,
                                                const float* __restrict__ Wk,
                                                const float* __restrict__ Wv,
                                                float2* __restrict__ KV,
                                                float* __restrict__ kpart) {
    __shared__ float As[2][2][16][68];
    __shared__ float Bs[2][2][16][36];
    __shared__ float red[8][16];
    __shared__ float colsum[32];
    __shared__ float Tile[64][33];
    int bid = blockIdx.x;
    int n0 = (bid % 15) * 32, m0 = (bid / 15) * 64;
    int tid = threadIdx.x;
    int kg = tid >> 8, t = tid & 255;
    int wid = tid >> 6, lane = tid & 63;
    if (tid < 32) colsum[tid] = 0.f;
    // ---- psi1 scale from partials ----
    float ps = 0.f, pq = 0.f;
    if (tid < 120) { ps = Spart[tid*2]; pq = Spart[tid*2+1]; }
    #pragma unroll
    for (int o = 32; o > 0; o >>= 1) { ps += __shfl_xor(ps, o, 64); pq += __shfl_xor(pq, o, 64); }
    if (lane == 0) { red[wid][0] = ps; red[wid][1] = pq; }
    __syncthreads();
    float S = 0.f, SQ = 0.f;
    #pragma unroll
    for (int w = 0; w < 8; ++w) { S += red[w][0]; SQ += red[w][1]; }
    const float invCC = 1.f / (480.f * 480.f);
    float mean = S * invCC;
    float var  = SQ * invCC - mean * mean;
    float s2 = g1[0] * rsqrtf(var + EPSN) * LOG2E;   // exp2-domain psi1 scale
    // ---- K-split double-buffered GEMM: A=Vc, B=exp2(s2*attn) on-the-fly ----
    int ty = t >> 4, tx = t & 15;
    float a00=0,a01=0,a10=0,a11=0,a20=0,a21=0,a30=0,a31=0;
    const float4 z4 = make_float4(0,0,0,0);
    int mrow = t >> 2, kq = (t & 3) * 4;
    bool am = (m0 + mrow) < N_TOK;
    const float* aptr = Vc + (m0 + mrow) * 480 + kg * 240 + kq;
    bool bact = t < 128;
    int nrow = t >> 2, bkq = (t & 3) * 4;
    const float* bptr = attn + (n0 + nrow) * 480 + kg * 240 + bkq;
    float bsum = 0.f;   // this thread's partial of colsum[nrow]
    const int NS = 15;
    float4 ra = am ? *(const float4*)(aptr) : z4;
    float4 rb = bact ? *(const float4*)(bptr) : z4;
    As[kg][0][kq+0][mrow]=ra.x; As[kg][0][kq+1][mrow]=ra.y;
    As[kg][0][kq+2][mrow]=ra.z; As[kg][0][kq+3][mrow]=ra.w;
    if (bact) {
        float e0 = fast_exp2(s2 * rb.x), e1 = fast_exp2(s2 * rb.y);
        float e2 = fast_exp2(s2 * rb.z), e3 = fast_exp2(s2 * rb.w);
        Bs[kg][0][bkq+0][nrow] = e0; Bs[kg][0][bkq+1][nrow] = e1;
        Bs[kg][0][bkq+2][nrow] = e2; Bs[kg][0][bkq+3][nrow] = e3;
        bsum += e0 + e1 + e2 + e3;
    }
    ra = am ? *(const float4*)(aptr + 16) : z4;
    rb = bact ? *(const float4*)(bptr + 16) : z4;
    __syncthreads();
    for (int s = 0; s < NS; ++s) {
        int b = s & 1;
        float4 fa = z4, fb = z4;
        if (s + 2 < NS) {
            fa = am ? *(const float4*)(aptr + (s+2)*16) : z4;
            fb = bact ? *(const float4*)(bptr + (s+2)*16) : z4;
        }
        GEMM_COMPUTE(As[kg][b], Bs[kg][b]);
        if (s + 1 < NS) {
            int nb = b ^ 1;
            As[kg][nb][kq+0][mrow]=ra.x; As[kg][nb][kq+1][mrow]=ra.y;
            As[kg][nb][kq+2][mrow]=ra.z; As[kg][nb][kq+3][mrow]=ra.w;
            if (bact) {
                float e0 = fast_exp2(s2 * rb.x), e1 = fast_exp2(s2 * rb.y);
                float e2 = fast_exp2(s2 * rb.z), e3 = fast_exp2(s2 * rb.w);
                Bs[kg][nb][bkq+0][nrow] = e0; Bs[kg][nb][bkq+1][nrow] = e1;
                Bs[kg][nb][bkq+2][nrow] = e2; Bs[kg][nb][bkq+3][nrow] = e3;
                bsum += e0 + e1 + e2 + e3;
            }
        }
        __syncthreads();
        ra = fa; rb = fb;
    }
    // ---- column sums -> reciprocals ----
    if (bact) atomicAdd(&colsum[nrow], bsum);
    __syncthreads();
    if (tid < 32) colsum[tid] = 1.f / colsum[tid];
    // ---- combine halves into Tile, scaled by INV[col] ----
    int r0 = ty*4, cc = tx*2;
    if (kg == 1) {
        Tile[r0+0][cc] = a00; Tile[r0+0][cc+1] = a01;
        Tile[r0+1][cc] = a10; Tile[r0+1][cc+1] = a11;
        Tile[r0+2][cc] = a20; Tile[r0+2][cc+1] = a21;
        Tile[r0+3][cc] = a30; Tile[r0+3][cc+1] = a31;
    }
    __syncthreads();
    if (kg == 0) {
        float i0 = colsum[cc], i1 = colsum[cc+1];
        Tile[r0+0][cc] = (Tile[r0+0][cc] + a00) * i0; Tile[r0+0][cc+1] = (Tile[r0+0][cc+1] + a01) * i1;
        Tile[r0+1][cc] = (Tile[r0+1][cc] + a10) * i0; Tile[r0+1][cc+1] = (Tile[r0+1][cc+1] + a11) * i1;
        Tile[r0+2][cc] = (Tile[r0+2][cc] + a20) * i0; Tile[r0+2][cc+1] = (Tile[r0+2][cc+1] + a21) * i1;
        Tile[r0+3][cc] = (Tile[r0+3][cc] + a30) * i0; Tile[r0+3][cc+1] = (Tile[r0+3][cc+1] + a31) * i1;
    }
    __syncthreads();
    // ---- K/V projection + per-block k-stats (sum, sumsq only) ----
    float su[4] = {0,0,0,0}, sq[4] = {0,0,0,0};
    {
        int e = tid;
        int tr = e >> 3, jj = e & 7;
        int tok = m0 + tr;
        bool act = tok < N_TOK;
        float c0 = Tile[tr][4*jj], c1 = Tile[tr][4*jj+1];
        float c2 = Tile[tr][4*jj+2], c3 = Tile[tr][4*jj+3];
        int m_kv = (n0/4 + jj) * 196 + tok;
        #pragma unroll
        for (int h = 0; h < 4; ++h) {
            float kh = c0*Wk[h] + c1*Wk[4+h] + c2*Wk[8+h] + c3*Wk[12+h];
            float vh = c0*Wv[h] + c1*Wv[4+h] + c2*Wv[8+h] + c3*Wv[12+h];
            if (act) {
                KV[h * M_KV + m_kv] = make_float2(kh, vh);
                su[h] += kh; sq[h] += kh * kh;
            }
        }
    }
    __syncthreads();
    #pragma unroll
    for (int h = 0; h < 4; ++h) {
        #pragma unroll
        for (int o = 32; o > 0; o >>= 1) {
            su[h] += __shfl_xor(su[h], o, 64);
            sq[h] += __shfl_xor(sq[h], o, 64);
        }
        if (lane == 0) { red[wid][h*2+0] = su[h]; red[wid][h*2+1] = sq[h]; }
    }
    __syncthreads();
    if (tid < 8) {
        int h = tid & 3, st = tid >> 2;   // st in {0,1}
        float r = 0.f;
        #pragma unroll
        for (int w = 0; w < 8; ++w) r += red[w][h*2+st];
        kpart[st * 256 + h * 64 + bid] = r;
    }
}

// -------- K4: branch attention, full-K per block, in-block finalize ---------
// grid = 196 blocks x 1024 threads. Wave w: head h = w>>2 over K-quarter p = w&3.
// No max-shift: exponent exp2(B2*k), |B2*k| << 126 (psi2-normalized scores).
#define QG 49
__global__ __launch_bounds__(1024) void k_branch(
        const float* __restrict__ emb1, const float* __restrict__ emb2,
        const float* __restrict__ emb3, const float* __restrict__ emb4,
        const float* __restrict__ Wq1, const float* __restrict__ Wq2,
        const float* __restrict__ Wq3, const float* __restrict__ Wq4,
        const float* __restrict__ g2v,
        const float2* __restrict__ KV, const float* __restrict__ kpart,
        const float* __restrict__ Wo1, const float* __restrict__ Wo2,
        const float* __restrict__ Wo3, const float* __restrict__ Wo4,
        float* __restrict__ out) {
    __shared__ float lsh[4][4][4];   // [head][quarter][j]
    __shared__ float ash[4][4][4];
    int tid = threadIdx.x;
    int w = tid >> 6, lane = tid & 63;
    int h = w >> 2, p = w & 3;                 // head, K-quarter
    int bid = blockIdx.x;
    int i = bid / QG, qg = bid % QG;
    const float* emb = (i == 0) ? emb1 : (i == 1) ? emb2 : (i == 2) ? emb3 : emb4;
    const float* Wq  = (i == 0) ? Wq1 : (i == 1) ? Wq2 : (i == 2) ? Wq3 : Wq4;
    float wq0 = Wq[h], wq1 = Wq[4+h], wq2 = Wq[8+h], wq3 = Wq[12+h];
    // ---- per-wave psi2 stats for (i, h) (duplicated across quarters) ----
    float s = 0.f, s2 = 0.f;
    #pragma unroll
    for (int r = 0; r < 4; ++r) {
        int t = lane + r * 64;
        if (t < N_TOK) {
            float Q = emb[t*4]*wq0 + emb[t*4+1]*wq1 + emb[t*4+2]*wq2 + emb[t*4+3]*wq3;
            s += Q; s2 += Q * Q;
        }
    }
    float ks = 0.f, kq2 = 0.f;
    if (lane < 60) {
        ks  = kpart[0*256 + h*64 + lane];
        kq2 = kpart[1*256 + h*64 + lane];
    }
    #pragma unroll
    for (int o = 32; o > 0; o >>= 1) {
        s += __shfl_xor(s, o, 64); s2 += __shfl_xor(s2, o, 64);
        ks += __shfl_xor(ks, o, 64); kq2 += __shfl_xor(kq2, o, 64);
    }
    float Qbar = s * (1.f/196.f), Q2bar = s2 * (1.f/196.f);
    float Kbar = ks * (1.f/(float)M_KV), K2bar = kq2 * (1.f/(float)M_KV);
    float mu = Qbar * Kbar;
    float var = Q2bar * K2bar - mu * mu;
    float sc = g2v[h] * rsqrtf(var + EPSN);
    // ---- 4 q's: beta in exp2 domain ----
    float B2[4];
    #pragma unroll
    for (int j = 0; j < 4; ++j) {
        int q = qg * 4 + j;
        float Qj = emb[q*4]*wq0 + emb[q*4+1]*wq1 + emb[q*4+2]*wq2 + emb[q*4+3]*wq3;
        B2[j] = Qj * sc * LOG2E;
    }
    // ---- K-quarter scan: float4 = 2 keys/lane/load, 4 loads in flight ----
    const float4* kv4 = (const float4*)(KV + h * M_KV);
    const int KQ = M_KV / 8;     // 2940 float4 per quarter
    int kstart = p * KQ, kendq = kstart + KQ;
    float l[4] = {0,0,0,0};
    float a[4] = {0,0,0,0};
#define PROC8(P) { \
        _Pragma("unroll") \
        for (int j = 0; j < 4; ++j) { \
            float x = fast_exp2(B2[j] * P.x); \
            l[j] += x; a[j] = fmaf(x, P.y, a[j]); \
            float y = fast_exp2(B2[j] * P.z); \
            l[j] += y; a[j] = fmaf(y, P.w, a[j]); \
        } }
    int k4 = kstart + lane;
    for (; k4 + 192 < kendq; k4 += 256) {
        float4 p0 = kv4[k4], p1 = kv4[k4+64], p2 = kv4[k4+128], p3 = kv4[k4+192];
        PROC8(p0); PROC8(p1); PROC8(p2); PROC8(p3);
    }
    for (; k4 < kendq; k4 += 64) { float4 pv = kv4[k4]; PROC8(pv); }
#undef PROC8
    // ---- per-wave reduce -> LDS partials ----
    #pragma unroll
    for (int j = 0; j < 4; ++j) {
        float lv = l[j], av = a[j];
        #pragma unroll
        for (int o = 32; o > 0; o >>= 1) { lv += __shfl_xor(lv, o, 64); av += __shfl_xor(av, o, 64); }
        if (lane == 0) { lsh[h][p][j] = lv; ash[h][p][j] = av; }
    }
    __syncthreads();
    // ---- in-block finalize ----
    if (tid < 4) {
        const float* Wo = (i == 0) ? Wo1 : (i == 1) ? Wo2 : (i == 2) ? Wo3 : Wo4;
        int j = tid;
        float c[4];
        #pragma unroll
        for (int hh = 0; hh < 4; ++hh) {
            float L = lsh[hh][0][j] + lsh[hh][1][j] + lsh[hh][2][j] + lsh[hh][3][j];
            float A = ash[hh][0][j] + ash[hh][1][j] + ash[hh][2][j] + ash[hh][3][j];
            c[hh] = A / L;
        }
        float4 o;
        o.x = c[0]*Wo[0] + c[1]*Wo[4] + c[2]*Wo[8]  + c[3]*Wo[12];
        o.y = c[0]*Wo[1] + c[1]*Wo[5] + c[2]*Wo[9]  + c[3]*Wo[13];
        o.z = c[0]*Wo[2] + c[1]*Wo[6] + c[2]*Wo[10] + c[3]*Wo[14];
        o.w = c[0]*Wo[3] + c[1]*Wo[7] + c[2]*Wo[11] + c[3]*Wo[15];
        *(float4*)(out + i * 784 + (qg * 4 + j) * 4) = o;
    }
}

extern "C" void kernel_launch(void* const* d_in, const int* in_sizes, int n_in,
                              void* d_out, int out_size, void* d_ws, size_t ws_size,
                              hipStream_t stream) {
    const float* emb1 = (const float*)d_in[0];
    const float* emb2 = (const float*)d_in[1];
    const float* emb3 = (const float*)d_in[2];
    const float* emb4 = (const float*)d_in[3];
    const float* embC = (const float*)d_in[4];
    const float* WqC  = (const float*)d_in[5];
    const float* WkC  = (const float*)d_in[6];
    const float* WvC  = (const float*)d_in[7];
    const float* Wq1  = (const float*)d_in[8];
    const float* Wq2  = (const float*)d_in[9];
    const float* Wq3  = (const float*)d_in[10];
    const float* Wq4  = (const float*)d_in[11];
    const float* Wk   = (const float*)d_in[12];
    const float* Wv   = (const float*)d_in[13];
    const float* Wo1  = (const float*)d_in[14];
    const float* Wo2  = (const float*)d_in[15];
    const float* Wo3  = (const float*)d_in[16];
    const float* Wo4  = (const float*)d_in[17];
    const float* g1   = (const float*)d_in[18];
    const float* g2   = (const float*)d_in[20];
    float* ws = (float*)d_ws;
    float* out = (float*)d_out;

    k_qkv<<<180, 512, 0, stream>>>(embC, WqC, WkC, WvC, ws);
    k_attn<<<dim3(15, 8), 512, 0, stream>>>(ws + OFF_QC, ws + OFF_KC,
                                            ws + OFF_ATTN, ws + OFF_SPART);
    k_thatkv<<<60, 512, 0, stream>>>(ws + OFF_VC, ws + OFF_ATTN, ws + OFF_SPART, g1,
                                     Wk, Wv, (float2*)(ws + OFF_KV), ws + OFF_KPART);
    k_branch<<<4 * QG, 1024, 0, stream>>>(emb1, emb2, emb3, emb4,
                                          Wq1, Wq2, Wq3, Wq4, g2,
                                          (const float2*)(ws + OFF_KV), ws + OFF_KPART,
                                          Wo1, Wo2, Wo3, Wo4, out);
}